// Round 13
// baseline (1055.874 us; speedup 1.0000x reference)
//
#include <hip/hip_runtime.h>

typedef __bf16 bf16x8 __attribute__((ext_vector_type(8)));
typedef float f32x4 __attribute__((ext_vector_type(4)));

union Frag {
    uint4 u4;
    bf16x8 b;
    unsigned short s[8];
};

__device__ __forceinline__ float b2f(unsigned int u) {
    return __uint_as_float((u & 0xffffu) << 16);
}
__device__ __forceinline__ unsigned short f2b(float f) {
    unsigned int x = __float_as_uint(f);
    unsigned int r = x + 0x7fffu + ((x >> 16) & 1u);  // RNE
    return (unsigned short)(r >> 16);
}

// ===========================================================================
// Weight conversion: fp32 -> bf16 hi + bf16 lo (w ≈ hi + lo to ~2^-18 rel)
// ===========================================================================
struct WPtrs {
    const float *bqkv, *bproj, *bfc1, *bfc2, *gqkv, *gproj, *gfc1, *gfc2;
};
__global__ __launch_bounds__(256) void conv_w2(WPtrs p, unsigned short* __restrict__ hi,
                                               unsigned short* __restrict__ lo) {
    int t = blockIdx.x * 256 + threadIdx.x;      // 393216 total
    float v;
    if (t < 49152)       v = p.bqkv[t];
    else if (t < 65536)  v = p.bproj[t - 49152];
    else if (t < 131072) v = p.bfc1[t - 65536];
    else if (t < 196608) v = p.bfc2[t - 131072];
    else if (t < 245760) v = p.gqkv[t - 196608];
    else if (t < 262144) v = p.gproj[t - 245760];
    else if (t < 327680) v = p.gfc1[t - 262144];
    else                 v = p.gfc2[t - 327680];
    unsigned short h = f2b(v);
    hi[t] = h;
    lo[t] = f2b(v - b2f(h));
}

// window_partition(x,7,7): fp32 x[1,128,224,224] -> bf16 xa[win*49+n][c]
__global__ __launch_bounds__(256) void gather_in(const float* __restrict__ x,
                                                 unsigned short* __restrict__ xa) {
    int t = blockIdx.x * 256 + threadIdx.x;       // 6422528
    int c = t & 127;
    int wn = t >> 7;
    int n = wn % 49;
    int w = wn / 49;
    int i = w >> 5, j = w & 31;
    int p = n / 7, q = n - p * 7;
    xa[t] = f2b(x[(size_t)c * 50176 + (i * 7 + p) * 224 + (j * 7 + q)]);
}

// ===========================================================================
// MFMA GEMM with split (hi+lo) weights: fp32-weight accuracy.
// ===========================================================================
__global__ __launch_bounds__(256) void gemm_bt(const unsigned short* __restrict__ X,
                                               const unsigned short* __restrict__ Whi,
                                               const unsigned short* __restrict__ Wlo,
                                               const float* __restrict__ bias,
                                               const float* __restrict__ resf,
                                               const float* __restrict__ resx,
                                               unsigned short* __restrict__ Yb,
                                               float* __restrict__ Yf,
                                               int M, int N, int K) {
    const int lane = threadIdx.x & 63;
    const int wid = threadIdx.x >> 6;
    const int m0 = blockIdx.y * 128 + wid * 32;
    const int n0 = blockIdx.x * 64;
    const int r = lane & 15, g = lane >> 4;

    f32x4 acc[2][4];
#pragma unroll
    for (int i = 0; i < 2; i++)
#pragma unroll
        for (int j = 0; j < 4; j++) acc[i][j] = (f32x4){0.f, 0.f, 0.f, 0.f};

    const unsigned short* xa0 = X + (size_t)(m0 + r) * K + g * 8;
    const unsigned short* xa1 = X + (size_t)(m0 + 16 + r) * K + g * 8;
    const size_t woff = (size_t)(n0 + r) * K + g * 8;

    for (int kc = 0; kc < K; kc += 32) {
        Frag a0, a1;
        a0.u4 = *(const uint4*)(xa0 + kc);
        a1.u4 = *(const uint4*)(xa1 + kc);
#pragma unroll
        for (int j = 0; j < 4; j++) {
            Frag bh, bl;
            bh.u4 = *(const uint4*)(Whi + woff + (size_t)j * 16 * K + kc);
            bl.u4 = *(const uint4*)(Wlo + woff + (size_t)j * 16 * K + kc);
            acc[0][j] = __builtin_amdgcn_mfma_f32_16x16x32_bf16(a0.b, bh.b, acc[0][j], 0, 0, 0);
            acc[0][j] = __builtin_amdgcn_mfma_f32_16x16x32_bf16(a0.b, bl.b, acc[0][j], 0, 0, 0);
            acc[1][j] = __builtin_amdgcn_mfma_f32_16x16x32_bf16(a1.b, bh.b, acc[1][j], 0, 0, 0);
            acc[1][j] = __builtin_amdgcn_mfma_f32_16x16x32_bf16(a1.b, bl.b, acc[1][j], 0, 0, 0);
        }
    }
#pragma unroll
    for (int i = 0; i < 2; i++) {
#pragma unroll
        for (int j = 0; j < 4; j++) {
            int col = n0 + j * 16 + r;
            float bia = bias ? bias[col] : 0.f;
#pragma unroll
            for (int rr = 0; rr < 4; rr++) {
                int rowi = m0 + i * 16 + g * 4 + rr;
                size_t idx = (size_t)rowi * N + col;
                float v = acc[i][j][rr] + bia;
                if (resf) v += resf[idx];
                if (resx) {
                    int w = rowi / 49, n = rowi - w * 49;
                    int ii = w >> 5, jj = w & 31;
                    int p = n / 7, q = n - p * 7;
                    v += resx[(size_t)col * 50176 + (ii * 7 + p) * 224 + (jj * 7 + q)];
                }
                if (Yb) Yb[idx] = f2b(v);
                if (Yf) Yf[idx] = v;
            }
        }
    }
}

// Block attention (7x7, N=49). One block per (window, head). QKV bf16 in.
__global__ __launch_bounds__(256) void attn_block7(const unsigned short* __restrict__ qkv,
                                                   const float* __restrict__ table,
                                                   unsigned short* __restrict__ out) {
    __shared__ __align__(16) unsigned int sq[49 * 17], sk[49 * 17], sv[49 * 17];
    __shared__ float ssc[49 * 49];
    const int bx = blockIdx.x;
    const int w = bx >> 2, h = bx & 3;
    const int tid = threadIdx.x;
    const unsigned int* qsrc = (const unsigned int*)qkv;

    for (int u = tid; u < 784; u += 256) {
        int i = u >> 4, du = u & 15;
        size_t rb = (size_t)(w * 49 + i) * 192 + h * 16 + du;
        sq[i * 17 + du] = qsrc[rb];
        sk[i * 17 + du] = qsrc[rb + 64];
        sv[i * 17 + du] = qsrc[rb + 128];
    }
    __syncthreads();

    for (int e = tid; e < 2401; e += 256) {
        int i = e / 49, j = e - i * 49;
        const unsigned int* qp = sq + i * 17;
        const unsigned int* kp = sk + j * 17;
        float dot = 0.f;
#pragma unroll
        for (int u = 0; u < 16; u++) {
            unsigned int a = qp[u], b = kp[u];
            dot += b2f(a) * b2f(b) + b2f(a >> 16) * b2f(b >> 16);
        }
        int ih = i / 7, iw2 = i - ih * 7, jh = j / 7, jw2 = j - jh * 7;
        int idx = (ih - jh + 6) * 13 + (iw2 - jw2 + 6);
        ssc[e] = dot * 5.65685424949238f + table[idx * 4 + h];
    }
    __syncthreads();

    if (tid < 49) {
        float* row = ssc + tid * 49;
        float mx = -1e30f;
        for (int j = 0; j < 49; j++) mx = fmaxf(mx, row[j]);
        float sum = 0.f;
        for (int j = 0; j < 49; j++) { float p = __expf(row[j] - mx); row[j] = p; sum += p; }
        float inv = 1.f / sum;
        for (int j = 0; j < 49; j++) row[j] *= inv;
    }
    __syncthreads();

    unsigned int* outu = (unsigned int*)out;
    for (int e = tid; e < 784; e += 256) {
        int i = e >> 4, dp = e & 15;
        const float* pr = ssc + i * 49;
        float a0 = 0.f, a1 = 0.f;
        for (int j = 0; j < 49; j++) {
            float p = pr[j];
            unsigned int vv = sv[j * 17 + dp];
            a0 += p * b2f(vv);
            a1 += p * b2f(vv >> 16);
        }
        outu[(size_t)(w * 49 + i) * 64 + h * 16 + dp] =
            (unsigned int)f2b(a0) | ((unsigned int)f2b(a1) << 16);
    }
}

// ===========================================================================
// Grid attention v4 (32x32, N=1024). 64-key tiles, 2 barriers/tile, 26.9 KB
// LDS (6 blocks/CU). Wave-uniform dim-group staging -> conflict-free V
// transpose; key-permuted positions (pos=4c+ch) so P writes are packed b32
// and PV operands are b128. exp2-domain softmax, bf16 bias, hoisted index.
// ===========================================================================
__global__ __launch_bounds__(256) void attn_grid32(const unsigned short* __restrict__ qkv,
                                                   const float* __restrict__ table,
                                                   unsigned short* __restrict__ out) {
    __shared__ unsigned short sbias[3972];
    __shared__ __align__(16) unsigned short sK[64][40];
    __shared__ __align__(16) unsigned short sVt[32][72];   // [dim][pos]
    __shared__ __align__(16) unsigned short plds[4][16][72];  // [wave][qrow][pos]
    const int tid = threadIdx.x;
    const int lane = tid & 63;
    const int wid = tid >> 6;
    const int b = blockIdx.x;                 // 49*4*16 = 3136
    const int w = b >> 6;
    const int h = (b >> 4) & 3;
    const int qb = b & 15;
    const int q0 = qb * 64 + wid * 16;
    const int c = lane & 15;
    const int g = lane >> 4;
    const size_t base = (size_t)w * 1024 * 384;
    const float scale2 = 5.65685424949238f * 1.4426950408889634f;  // sqrt(32)*log2(e)

    for (int i = tid; i < 3969; i += 256)
        sbias[i] = f2b(table[i * 4 + h] * 1.4426950408889634f);

    Frag qf;                                   // A-frag: Q[m=c][k=g*8..+7]
    qf.u4 = *(const uint4*)(qkv + base + (size_t)(q0 + c) * 384 + h * 32 + g * 8);

    float m_[4], l_[4];
    int qbias[4];
    f32x4 o0 = {0.f, 0.f, 0.f, 0.f}, o1 = {0.f, 0.f, 0.f, 0.f};
#pragma unroll
    for (int rr = 0; rr < 4; rr++) {
        m_[rr] = -1e30f;
        l_[rr] = 0.f;
        int ig = q0 + g * 4 + rr;
        qbias[rr] = (ig >> 5) * 63 + (ig & 31) + 31 * 63 + 31 - c;
    }

    // staging: key = tid&63 (lane), dim group = 8*(wave id) -- wave-uniform
    const int skey = lane;
    const int sd = wid * 8;
    const int vpos = 4 * (skey & 15) + (skey >> 4);   // pos(k) = 4c + ch
    const unsigned short* kgp = qkv + base + 128 + h * 32 + sd;
    const unsigned short* vgp = qkv + base + 256 + h * 32 + sd;

    for (int jc = 0; jc < 1024; jc += 64) {
        __syncthreads();                       // prev tile's K/V reads done
        size_t roff = (size_t)(jc + skey) * 384;
        *(uint4*)(&sK[skey][sd]) = *(const uint4*)(kgp + roff);
        Frag vv;
        vv.u4 = *(const uint4*)(vgp + roff);
#pragma unroll
        for (int z = 0; z < 8; ++z) sVt[sd + z][vpos] = vv.s[z];  // conflict-free
        __syncthreads();

        // QK^T: 4 chunks of 16 keys
        f32x4 s4[4];
        const f32x4 z4 = {0.f, 0.f, 0.f, 0.f};
#pragma unroll
        for (int ch = 0; ch < 4; ++ch) {
            Frag kf;
            kf.u4 = *(const uint4*)(&sK[ch * 16 + c][g * 8]);
            s4[ch] = __builtin_amdgcn_mfma_f32_16x16x32_bf16(qf.b, kf.b, z4, 0, 0, 0);
        }
        // online softmax over the 64-key chunk (log2 domain)
#pragma unroll
        for (int rr = 0; rr < 4; ++rr) {
            int bias0 = qbias[rr] - (jc >> 5) * 63;
            float sv2[4];
            float cm = -1e30f;
#pragma unroll
            for (int ch = 0; ch < 4; ++ch) {
                int idx = bias0 - (ch >> 1) * 63 - (ch & 1) * 16;
                float v = s4[ch][rr] * scale2 + b2f(sbias[idx]);
                sv2[ch] = v;
                cm = fmaxf(cm, v);
            }
#pragma unroll
            for (int off = 1; off < 16; off <<= 1) cm = fmaxf(cm, __shfl_xor(cm, off, 64));
            float mn = fmaxf(m_[rr], cm);
            float alpha = exp2f(m_[rr] - mn);
            m_[rr] = mn;
            float p0 = exp2f(sv2[0] - mn);
            float p1 = exp2f(sv2[1] - mn);
            float p2 = exp2f(sv2[2] - mn);
            float p3 = exp2f(sv2[3] - mn);
            float ps = (p0 + p1) + (p2 + p3);
            // P at positions 4c..4c+3 (pos=4c+ch): two packed b32 writes
            unsigned int* prow = (unsigned int*)(&plds[wid][g * 4 + rr][c * 4]);
            prow[0] = (unsigned int)f2b(p0) | ((unsigned int)f2b(p1) << 16);
            prow[1] = (unsigned int)f2b(p2) | ((unsigned int)f2b(p3) << 16);
#pragma unroll
            for (int off = 1; off < 16; off <<= 1) ps += __shfl_xor(ps, off, 64);
            l_[rr] = l_[rr] * alpha + ps;
            o0[rr] *= alpha;
            o1[rr] *= alpha;
        }
        // PV over positions: 2 chunks of 32; all operands b128; plds per-wave
#pragma unroll
        for (int ch2 = 0; ch2 < 2; ++ch2) {
            Frag pf, vf0, vf1;
            pf.u4 = *(const uint4*)(&plds[wid][c][ch2 * 32 + g * 8]);
            vf0.u4 = *(const uint4*)(&sVt[c][ch2 * 32 + g * 8]);
            vf1.u4 = *(const uint4*)(&sVt[16 + c][ch2 * 32 + g * 8]);
            o0 = __builtin_amdgcn_mfma_f32_16x16x32_bf16(pf.b, vf0.b, o0, 0, 0, 0);
            o1 = __builtin_amdgcn_mfma_f32_16x16x32_bf16(pf.b, vf1.b, o1, 0, 0, 0);
        }
    }
#pragma unroll
    for (int rr = 0; rr < 4; rr++) {
        float inv = 1.0f / l_[rr];
        int row = q0 + g * 4 + rr;
        size_t ob = (size_t)(w * 1024 + row) * 128 + h * 32;
        out[ob + c] = f2b(o0[rr] * inv);
        out[ob + 16 + c] = f2b(o1[rr] * inv);
    }
}

// LayerNorm on fp32 input; writes bf16 (GEMM input) + fp32 (MLP shortcut).
__global__ __launch_bounds__(256) void ln_f(const float* __restrict__ in,
                                            const float* __restrict__ gam,
                                            const float* __restrict__ bet,
                                            unsigned short* __restrict__ outb,
                                            float* __restrict__ outf) {
    int token = blockIdx.x * 4 + (threadIdx.x >> 6);
    int lane = threadIdx.x & 63;
    float2 v = ((const float2*)in)[(size_t)token * 64 + lane];
    float s = v.x + v.y, s2 = v.x * v.x + v.y * v.y;
#pragma unroll
    for (int off = 1; off < 64; off <<= 1) {
        s += __shfl_xor(s, off, 64);
        s2 += __shfl_xor(s2, off, 64);
    }
    float mean = s * (1.f / 128.f);
    float var = s2 * (1.f / 128.f) - mean * mean;
    float inv = rsqrtf(var + 1e-5f);
    float2 gv = ((const float2*)gam)[lane];
    float2 bv = ((const float2*)bet)[lane];
    float y0 = (v.x - mean) * inv * gv.x + bv.x;
    float y1 = (v.y - mean) * inv * gv.y + bv.y;
    ((unsigned int*)outb)[(size_t)token * 64 + lane] =
        (unsigned int)f2b(y0) | ((unsigned int)f2b(y1) << 16);
    ((float2*)outf)[(size_t)token * 64 + lane] = make_float2(y0, y1);
}

// unbind(7)+transpose+partition(32): fp32 ya -> bf16 xb + fp32 xbf
__global__ __launch_bounds__(256) void remap_ab_f(const float* __restrict__ ya,
                                                  unsigned short* __restrict__ xb,
                                                  float* __restrict__ xbf) {
    int t = blockIdx.x * 256 + threadIdx.x;
    int c2 = t & 127;
    int tok = (t >> 7) & 1023;
    int W2 = t >> 17;
    int P = tok >> 5, Q = tok & 31;
    int I = W2 / 7, J = W2 - I * 7;
    int y = I * 32 + P, x2 = J * 32 + Q;
    int f = y * 28672 + x2 * 128 + c2;
    int c = f / 50176;
    int rm = f - c * 50176;
    int i = rm / 1568;
    int r2 = rm - i * 1568;
    int p = r2 / 224;
    int r3 = r2 - p * 224;
    int q = r3 >> 5, j = r3 & 31;
    float val = ya[((size_t)((i * 32 + j) * 49 + p * 7 + q)) * 128 + c];
    xb[t] = f2b(val);
    xbf[t] = val;
}

// unbind(32)+final transpose: fp32 yb -> fp32 out[1,128,224,224]
__global__ __launch_bounds__(256) void remap_out_f(const float* __restrict__ yb,
                                                   float* __restrict__ out) {
    int t = blockIdx.x * 256 + threadIdx.x;
    int c2 = t / 50176;
    int rem = t - c2 * 50176;
    int y = rem / 224;
    int x2 = rem - y * 224;
    int g = y * 28672 + x2 * 128 + c2;
    int c = g / 50176;
    int r = g - c * 50176;
    int I = r / 7168;
    int r2 = r - I * 7168;
    int P = r2 / 224;
    int r3 = r2 - P * 224;
    int Q = r3 / 7, J = r3 - Q * 7;
    out[t] = yb[((size_t)((I * 7 + J) * 1024 + P * 32 + Q)) * 128 + c];
}

// ===========================================================================
// FALLBACK PATH (proven round-7 scalar kernels; used if ws_size too small)
// ===========================================================================
__global__ __launch_bounds__(256) void remap_ab_s(const unsigned short* __restrict__ ya,
                                                  unsigned short* __restrict__ xb) {
    int t = blockIdx.x * 256 + threadIdx.x;
    int c2 = t & 127;
    int tok = (t >> 7) & 1023;
    int W2 = t >> 17;
    int P = tok >> 5, Q = tok & 31;
    int I = W2 / 7, J = W2 - I * 7;
    int y = I * 32 + P, x2 = J * 32 + Q;
    int f = y * 28672 + x2 * 128 + c2;
    int c = f / 50176;
    int rm = f - c * 50176;
    int i = rm / 1568;
    int r2 = rm - i * 1568;
    int p = r2 / 224;
    int r3 = r2 - p * 224;
    int q = r3 >> 5, j = r3 & 31;
    xb[t] = ya[((size_t)((i * 32 + j) * 49 + p * 7 + q)) * 128 + c];
}
__global__ __launch_bounds__(256) void remap_out_s(const unsigned short* __restrict__ yb,
                                                   float* __restrict__ out) {
    int t = blockIdx.x * 256 + threadIdx.x;
    int c2 = t / 50176;
    int rem = t - c2 * 50176;
    int y = rem / 224;
    int x2 = rem - y * 224;
    int g = y * 28672 + x2 * 128 + c2;
    int c = g / 50176;
    int r = g - c * 50176;
    int I = r / 7168;
    int r2 = r - I * 7168;
    int P = r2 / 224;
    int r3 = r2 - P * 224;
    int Q = r3 / 7, J = r3 - Q * 7;
    out[t] = b2f(yb[((size_t)((I * 7 + J) * 1024 + P * 32 + Q)) * 128 + c]);
}
__global__ __launch_bounds__(256) void gemm_w32(const unsigned short* __restrict__ X,
                                                const float* __restrict__ W,
                                                const float* __restrict__ bias,
                                                const unsigned short* __restrict__ res,
                                                unsigned short* __restrict__ Y,
                                                int M, int N, int K) {
    long long t = (long long)blockIdx.x * 256 + threadIdx.x;
    if (t >= (long long)M * N) return;
    int m = (int)(t / N);
    int n = (int)(t - (long long)m * N);
    const unsigned short* xr = X + (size_t)m * K;
    const float* wr = W + (size_t)n * K;
    float acc = bias ? bias[n] : 0.f;
    for (int k = 0; k < K; ++k) acc += b2f(xr[k]) * wr[k];
    if (res) acc += b2f(res[t]);
    Y[t] = f2b(acc);
}
__global__ __launch_bounds__(256) void attn_block7_fused(const unsigned short* __restrict__ xa,
                                                         const float* __restrict__ qw,
                                                         const float* __restrict__ table,
                                                         unsigned short* __restrict__ out) {
    __shared__ unsigned short sx[49 * 128];
    __shared__ float sq[49 * 32], sk[49 * 32], sv[49 * 32];
    __shared__ float ssc[49 * 49];
    const int bx = blockIdx.x;
    const int w = bx >> 2, h = bx & 3;
    const int tid = threadIdx.x;
    for (int u = tid; u < 6272; u += 256) sx[u] = xa[(size_t)(w * 49) * 128 + u];
    __syncthreads();
    for (int e = tid; e < 4704; e += 256) {
        int which = e / 1568;
        int rem = e - which * 1568;
        int n = rem >> 5, d = rem & 31;
        const float* wr = qw + (size_t)(which * 128 + h * 32 + d) * 128;
        const unsigned short* xr = sx + n * 128;
        float acc = 0.f;
        for (int k = 0; k < 128; ++k) acc += b2f(xr[k]) * wr[k];
        if (which == 0) sq[n * 32 + d] = acc;
        else if (which == 1) sk[n * 32 + d] = acc;
        else sv[n * 32 + d] = acc;
    }
    __syncthreads();
    for (int e = tid; e < 2401; e += 256) {
        int i = e / 49, j = e - i * 49;
        float dot = 0.f;
        for (int d = 0; d < 32; ++d) dot += sq[i * 32 + d] * sk[j * 32 + d];
        int ih = i / 7, iw2 = i - ih * 7, jh = j / 7, jw2 = j - jh * 7;
        int idx = (ih - jh + 6) * 13 + (iw2 - jw2 + 6);
        ssc[e] = dot * 5.65685424949238f + table[idx * 4 + h];
    }
    __syncthreads();
    if (tid < 49) {
        float* row = ssc + tid * 49;
        float mx = -1e30f;
        for (int j = 0; j < 49; j++) mx = fmaxf(mx, row[j]);
        float sum = 0.f;
        for (int j = 0; j < 49; j++) { float p = __expf(row[j] - mx); row[j] = p; sum += p; }
        float inv = 1.f / sum;
        for (int j = 0; j < 49; j++) row[j] *= inv;
    }
    __syncthreads();
    for (int e = tid; e < 1568; e += 256) {
        int i = e >> 5, d = e & 31;
        const float* pr = ssc + i * 49;
        float a = 0.f;
        for (int j = 0; j < 49; j++) a += pr[j] * sv[j * 32 + d];
        out[(size_t)(w * 49 + i) * 128 + h * 32 + d] = f2b(a);
    }
}
__global__ __launch_bounds__(256) void kv_head(const unsigned short* __restrict__ xa,
                                               const float* __restrict__ qw,
                                               int h,
                                               unsigned short* __restrict__ kvh) {
    int t = blockIdx.x * 256 + threadIdx.x;
    int tok = t >> 6, e = t & 63;
    int which = (e < 32) ? 1 : 2;
    int d = e & 31;
    const float* wr = qw + (size_t)(which * 128 + h * 32 + d) * 128;
    const unsigned short* xr = xa + (size_t)tok * 128;
    float acc = 0.f;
    for (int k = 0; k < 128; ++k) acc += b2f(xr[k]) * wr[k];
    kvh[t] = f2b(acc);
}
__global__ __launch_bounds__(256) void attn_grid_head(const unsigned short* __restrict__ xa,
                                                      const unsigned short* __restrict__ kvh,
                                                      const float* __restrict__ qw,
                                                      const float* __restrict__ table,
                                                      int h,
                                                      unsigned short* __restrict__ out) {
    __shared__ float sq[32];
    __shared__ float ss[1024];
    __shared__ float red[256];
    __shared__ float pvp[256];
    const int w = blockIdx.x >> 4;
    const int qg = blockIdx.x & 15;
    const int tid = threadIdx.x;
    const float scale = 5.65685424949238f;
    for (int qq = 0; qq < 64; ++qq) {
        const int qi = qg * 64 + qq;
        const int tok = w * 1024 + qi;
        if (tid < 32) {
            const float* wr = qw + (size_t)(h * 32 + tid) * 128;
            const unsigned short* xr = xa + (size_t)tok * 128;
            float acc = 0.f;
            for (int k = 0; k < 128; ++k) acc += b2f(xr[k]) * wr[k];
            sq[tid] = acc;
        }
        __syncthreads();
        const int ihq = qi >> 5, iwq = qi & 31;
        for (int k = tid; k < 1024; k += 256) {
            const unsigned short* kp = kvh + (size_t)(w * 1024 + k) * 64;
            float dot = 0.f;
            for (int d = 0; d < 32; ++d) dot += sq[d] * b2f(kp[d]);
            int jh2 = k >> 5, jw2 = k & 31;
            int idx = (ihq - jh2 + 31) * 63 + (iwq - jw2 + 31);
            ss[k] = dot * scale + table[idx * 4 + h];
        }
        __syncthreads();
        float m = fmaxf(fmaxf(ss[tid], ss[tid + 256]), fmaxf(ss[tid + 512], ss[tid + 768]));
        red[tid] = m;
        __syncthreads();
        for (int s = 128; s > 0; s >>= 1) {
            if (tid < s) red[tid] = fmaxf(red[tid], red[tid + s]);
            __syncthreads();
        }
        m = red[0];
        __syncthreads();
        float ps = 0.f;
        for (int k = tid; k < 1024; k += 256) {
            float p = __expf(ss[k] - m);
            ss[k] = p;
            ps += p;
        }
        red[tid] = ps;
        __syncthreads();
        for (int s = 128; s > 0; s >>= 1) {
            if (tid < s) red[tid] += red[tid + s];
            __syncthreads();
        }
        float l = red[0];
        int kc = tid >> 5, d = tid & 31;
        float a = 0.f;
        const unsigned short* vbase = kvh + (size_t)(w * 1024) * 64 + 32 + d;
        for (int k = kc * 128; k < kc * 128 + 128; ++k) a += ss[k] * b2f(vbase[(size_t)k * 64]);
        pvp[tid] = a;
        __syncthreads();
        if (tid < 32) {
            float o = 0.f;
            for (int c2 = 0; c2 < 8; ++c2) o += pvp[c2 * 32 + tid];
            out[(size_t)tok * 128 + h * 32 + tid] = f2b(o / l);
        }
        __syncthreads();
    }
}
__global__ __launch_bounds__(256) void mlp_fused(const unsigned short* __restrict__ xin,
                                                 const float* __restrict__ fc1w,
                                                 const float* __restrict__ fc1b,
                                                 const float* __restrict__ fc2w,
                                                 const float* __restrict__ fc2b,
                                                 unsigned short* __restrict__ out) {
    __shared__ float sxr[128];
    __shared__ float sh[512];
    const int tok = blockIdx.x;
    const int tid = threadIdx.x;
    if (tid < 128) sxr[tid] = b2f(xin[(size_t)tok * 128 + tid]);
    __syncthreads();
    for (int hh = tid; hh < 512; hh += 256) {
        const float* wr = fc1w + (size_t)hh * 128;
        float acc = fc1b[hh];
        for (int k = 0; k < 128; ++k) acc += sxr[k] * wr[k];
        sh[hh] = acc;
    }
    __syncthreads();
    if (tid < 128) {
        const float* wr = fc2w + (size_t)tid * 512;
        float acc = fc2b[tid];
        for (int k = 0; k < 512; ++k) acc += sh[k] * wr[k];
        out[(size_t)tok * 128 + tid] = f2b(acc + sxr[tid]);
    }
}
__global__ __launch_bounds__(256) void ln_k(const unsigned short* __restrict__ in,
                                            const float* __restrict__ gam,
                                            const float* __restrict__ bet,
                                            unsigned short* __restrict__ out) {
    int token = blockIdx.x * 4 + (threadIdx.x >> 6);
    int lane = threadIdx.x & 63;
    const unsigned int* row = (const unsigned int*)in + (size_t)token * 64;
    unsigned int v = row[lane];
    float x0 = b2f(v), x1 = b2f(v >> 16);
    float s = x0 + x1, s2 = x0 * x0 + x1 * x1;
#pragma unroll
    for (int off = 1; off < 64; off <<= 1) {
        s += __shfl_xor(s, off, 64);
        s2 += __shfl_xor(s2, off, 64);
    }
    float mean = s * (1.f / 128.f);
    float var = s2 * (1.f / 128.f) - mean * mean;
    float inv = rsqrtf(var + 1e-5f);
    float2 gv = ((const float2*)gam)[lane];
    float2 bv = ((const float2*)bet)[lane];
    float y0 = (x0 - mean) * inv * gv.x + bv.x;
    float y1 = (x1 - mean) * inv * gv.y + bv.y;
    ((unsigned int*)out)[(size_t)token * 64 + lane] =
        (unsigned int)f2b(y0) | ((unsigned int)f2b(y1) << 16);
}

// ===========================================================================
extern "C" void kernel_launch(void* const* d_in, const int* in_sizes, int n_in,
                              void* d_out, int out_size, void* d_ws, size_t ws_size,
                              hipStream_t stream) {
    (void)in_sizes; (void)n_in; (void)out_size;
    const float* x = (const float*)d_in[0];
    unsigned short* ws = (unsigned short*)d_ws;
    const int M = 50176;
    dim3 blk(256);
    #define F32(i) ((const float*)d_in[i])

    if (ws_size >= 117178368ull) {
        // ---------------- FAST PATH (MFMA, split weights) ----------------
        unsigned short* WHI = ws;
        unsigned short* WLO = ws + 393216;
        unsigned short* XA  = ws + 786432;
        unsigned short* AT  = ws + 7208960;
        unsigned short* Y2  = ws + 13631488;
        float*          R1  = (float*)(ws + 20054016);
        unsigned short* BIG = ws + 32899072;
        float*          Yf  = (float*)d_out;          // Y1f scratch
        float*          YOB = (float*)XA;             // stage-B fp32 out (XA∪AT)

        WPtrs wp = {F32(2), F32(3), F32(7), F32(9), F32(12), F32(13), F32(17), F32(19)};
        const size_t oqkv = 0, oproj = 49152, ofc1 = 65536, ofc2 = 131072;
        const size_t goff = 196608;

        conv_w2<<<1536, blk, 0, stream>>>(wp, WHI, WLO);
        gather_in<<<25088, blk, 0, stream>>>(x, XA);

        // ---- stage A ----
        gemm_bt<<<dim3(6, 392), blk, 0, stream>>>(XA, WHI + oqkv, WLO + oqkv, nullptr,
                                                  nullptr, nullptr, BIG, nullptr, M, 384, 128);
        attn_block7<<<4096, blk, 0, stream>>>(BIG, F32(1), AT);
        gemm_bt<<<dim3(2, 392), blk, 0, stream>>>(AT, WHI + oproj, WLO + oproj, F32(4),
                                                  nullptr, x, nullptr, Yf, M, 128, 128);
        ln_f<<<12544, blk, 0, stream>>>(Yf, F32(5), F32(6), Y2, R1);
        gemm_bt<<<dim3(8, 392), blk, 0, stream>>>(Y2, WHI + ofc1, WLO + ofc1, F32(8),
                                                  nullptr, nullptr, BIG, nullptr, M, 512, 128);
        gemm_bt<<<dim3(2, 392), blk, 0, stream>>>(BIG, WHI + ofc2, WLO + ofc2, F32(10),
                                                  R1, nullptr, nullptr, Yf, M, 128, 512);
        remap_ab_f<<<25088, blk, 0, stream>>>(Yf, XA, R1);

        // ---- stage B ----
        gemm_bt<<<dim3(6, 392), blk, 0, stream>>>(XA, WHI + goff + oqkv, WLO + goff + oqkv,
                                                  nullptr, nullptr, nullptr, BIG, nullptr, M, 384, 128);
        attn_grid32<<<3136, blk, 0, stream>>>(BIG, F32(11), AT);
        gemm_bt<<<dim3(2, 392), blk, 0, stream>>>(AT, WHI + goff + oproj, WLO + goff + oproj,
                                                  F32(14), R1, nullptr, nullptr, Yf, M, 128, 128);
        ln_f<<<12544, blk, 0, stream>>>(Yf, F32(15), F32(16), Y2, R1);
        gemm_bt<<<dim3(8, 392), blk, 0, stream>>>(Y2, WHI + goff + ofc1, WLO + goff + ofc1,
                                                  F32(18), nullptr, nullptr, BIG, nullptr, M, 512, 128);
        gemm_bt<<<dim3(2, 392), blk, 0, stream>>>(BIG, WHI + goff + ofc2, WLO + goff + ofc2,
                                                  F32(20), R1, nullptr, nullptr, YOB, M, 128, 512);
        remap_out_f<<<25088, blk, 0, stream>>>(YOB, (float*)d_out);
    } else {
        // ---------------- FALLBACK (proven round-7 scalar path) ----------------
        unsigned short* XA  = ws;
        unsigned short* AT  = XA + 6422528;
        unsigned short* KVh = AT + 6422528;
        unsigned short* Yd  = (unsigned short*)d_out;

        gather_in<<<25088, blk, 0, stream>>>(x, XA);
        attn_block7_fused<<<4096, blk, 0, stream>>>(XA, F32(2), F32(1), AT);
        gemm_w32<<<25088, blk, 0, stream>>>(AT, F32(3), F32(4), XA, Yd, M, 128, 128);
        ln_k<<<12544, blk, 0, stream>>>(Yd, F32(5), F32(6), Yd);
        mlp_fused<<<50176, blk, 0, stream>>>(Yd, F32(7), F32(8), F32(9), F32(10), AT);
        remap_ab_s<<<25088, blk, 0, stream>>>(AT, XA);
        for (int h = 0; h < 4; ++h) {
            kv_head<<<12544, blk, 0, stream>>>(XA, F32(12), h, KVh);
            attn_grid_head<<<784, blk, 0, stream>>>(XA, KVh, F32(12), F32(11), h, AT);
        }
        gemm_w32<<<25088, blk, 0, stream>>>(AT, F32(13), F32(14), XA, Yd, M, 128, 128);
        ln_k<<<12544, blk, 0, stream>>>(Yd, F32(15), F32(16), Yd);
        mlp_fused<<<50176, blk, 0, stream>>>(Yd, F32(17), F32(18), F32(19), F32(20), AT);
        remap_out_s<<<25088, blk, 0, stream>>>(AT, (float*)d_out);
    }
    #undef F32
}

// Round 14
// 931.926 us; speedup vs baseline: 1.1330x; 1.1330x over previous
//
#include <hip/hip_runtime.h>

typedef __bf16 bf16x8 __attribute__((ext_vector_type(8)));
typedef float f32x4 __attribute__((ext_vector_type(4)));
typedef float f32x4u __attribute__((ext_vector_type(4), aligned(4)));

union Frag {
    uint4 u4;
    bf16x8 b;
    unsigned short s[8];
};

__device__ __forceinline__ float b2f(unsigned int u) {
    return __uint_as_float((u & 0xffffu) << 16);
}
__device__ __forceinline__ unsigned short f2b(float f) {
    unsigned int x = __float_as_uint(f);
    unsigned int r = x + 0x7fffu + ((x >> 16) & 1u);  // RNE
    return (unsigned short)(r >> 16);
}

// ===========================================================================
// Weight conversion: fp32 -> bf16 hi + bf16 lo (w ≈ hi + lo to ~2^-18 rel)
// ===========================================================================
struct WPtrs {
    const float *bqkv, *bproj, *bfc1, *bfc2, *gqkv, *gproj, *gfc1, *gfc2;
};
__global__ __launch_bounds__(256) void conv_w2(WPtrs p, unsigned short* __restrict__ hi,
                                               unsigned short* __restrict__ lo) {
    int t = blockIdx.x * 256 + threadIdx.x;      // 393216 total
    float v;
    if (t < 49152)       v = p.bqkv[t];
    else if (t < 65536)  v = p.bproj[t - 49152];
    else if (t < 131072) v = p.bfc1[t - 65536];
    else if (t < 196608) v = p.bfc2[t - 131072];
    else if (t < 245760) v = p.gqkv[t - 196608];
    else if (t < 262144) v = p.gproj[t - 245760];
    else if (t < 327680) v = p.gfc1[t - 262144];
    else                 v = p.gfc2[t - 327680];
    unsigned short h = f2b(v);
    hi[t] = h;
    lo[t] = f2b(v - b2f(h));
}

// Per-head contiguous grid-bias table, pre-scaled by 1/sqrt(32) (C-operand).
__global__ __launch_bounds__(256) void conv_bias(const float* __restrict__ table,
                                                 float* __restrict__ tp) {
    int t = blockIdx.x * 256 + threadIdx.x;      // 15876 total
    if (t >= 15876) return;
    int h = t / 3969;
    int idx = t - h * 3969;
    tp[h * 3972 + idx] = table[idx * 4 + h] * 0.17677669529663689f;
}

// window_partition(x,7,7): fp32 x[1,128,224,224] -> bf16 xa[win*49+n][c]
__global__ __launch_bounds__(256) void gather_in(const float* __restrict__ x,
                                                 unsigned short* __restrict__ xa) {
    int t = blockIdx.x * 256 + threadIdx.x;       // 6422528
    int c = t & 127;
    int wn = t >> 7;
    int n = wn % 49;
    int w = wn / 49;
    int i = w >> 5, j = w & 31;
    int p = n / 7, q = n - p * 7;
    xa[t] = f2b(x[(size_t)c * 50176 + (i * 7 + p) * 224 + (j * 7 + q)]);
}

// ===========================================================================
// MFMA GEMM with split (hi+lo) weights: fp32-weight accuracy.
// ===========================================================================
__global__ __launch_bounds__(256) void gemm_bt(const unsigned short* __restrict__ X,
                                               const unsigned short* __restrict__ Whi,
                                               const unsigned short* __restrict__ Wlo,
                                               const float* __restrict__ bias,
                                               const float* __restrict__ resf,
                                               const float* __restrict__ resx,
                                               unsigned short* __restrict__ Yb,
                                               float* __restrict__ Yf,
                                               int M, int N, int K) {
    const int lane = threadIdx.x & 63;
    const int wid = threadIdx.x >> 6;
    const int m0 = blockIdx.y * 128 + wid * 32;
    const int n0 = blockIdx.x * 64;
    const int r = lane & 15, g = lane >> 4;

    f32x4 acc[2][4];
#pragma unroll
    for (int i = 0; i < 2; i++)
#pragma unroll
        for (int j = 0; j < 4; j++) acc[i][j] = (f32x4){0.f, 0.f, 0.f, 0.f};

    const unsigned short* xa0 = X + (size_t)(m0 + r) * K + g * 8;
    const unsigned short* xa1 = X + (size_t)(m0 + 16 + r) * K + g * 8;
    const size_t woff = (size_t)(n0 + r) * K + g * 8;

    for (int kc = 0; kc < K; kc += 32) {
        Frag a0, a1;
        a0.u4 = *(const uint4*)(xa0 + kc);
        a1.u4 = *(const uint4*)(xa1 + kc);
#pragma unroll
        for (int j = 0; j < 4; j++) {
            Frag bh, bl;
            bh.u4 = *(const uint4*)(Whi + woff + (size_t)j * 16 * K + kc);
            bl.u4 = *(const uint4*)(Wlo + woff + (size_t)j * 16 * K + kc);
            acc[0][j] = __builtin_amdgcn_mfma_f32_16x16x32_bf16(a0.b, bh.b, acc[0][j], 0, 0, 0);
            acc[0][j] = __builtin_amdgcn_mfma_f32_16x16x32_bf16(a0.b, bl.b, acc[0][j], 0, 0, 0);
            acc[1][j] = __builtin_amdgcn_mfma_f32_16x16x32_bf16(a1.b, bh.b, acc[1][j], 0, 0, 0);
            acc[1][j] = __builtin_amdgcn_mfma_f32_16x16x32_bf16(a1.b, bl.b, acc[1][j], 0, 0, 0);
        }
    }
#pragma unroll
    for (int i = 0; i < 2; i++) {
#pragma unroll
        for (int j = 0; j < 4; j++) {
            int col = n0 + j * 16 + r;
            float bia = bias ? bias[col] : 0.f;
#pragma unroll
            for (int rr = 0; rr < 4; rr++) {
                int rowi = m0 + i * 16 + g * 4 + rr;
                size_t idx = (size_t)rowi * N + col;
                float v = acc[i][j][rr] + bia;
                if (resf) v += resf[idx];
                if (resx) {
                    int w = rowi / 49, n = rowi - w * 49;
                    int ii = w >> 5, jj = w & 31;
                    int p = n / 7, q = n - p * 7;
                    v += resx[(size_t)col * 50176 + (ii * 7 + p) * 224 + (jj * 7 + q)];
                }
                if (Yb) Yb[idx] = f2b(v);
                if (Yf) Yf[idx] = v;
            }
        }
    }
}

// Block attention (7x7, N=49). One block per (window, head). QKV bf16 in.
__global__ __launch_bounds__(256) void attn_block7(const unsigned short* __restrict__ qkv,
                                                   const float* __restrict__ table,
                                                   unsigned short* __restrict__ out) {
    __shared__ __align__(16) unsigned int sq[49 * 17], sk[49 * 17], sv[49 * 17];
    __shared__ float ssc[49 * 49];
    const int bx = blockIdx.x;
    const int w = bx >> 2, h = bx & 3;
    const int tid = threadIdx.x;
    const unsigned int* qsrc = (const unsigned int*)qkv;

    for (int u = tid; u < 784; u += 256) {
        int i = u >> 4, du = u & 15;
        size_t rb = (size_t)(w * 49 + i) * 192 + h * 16 + du;
        sq[i * 17 + du] = qsrc[rb];
        sk[i * 17 + du] = qsrc[rb + 64];
        sv[i * 17 + du] = qsrc[rb + 128];
    }
    __syncthreads();

    for (int e = tid; e < 2401; e += 256) {
        int i = e / 49, j = e - i * 49;
        const unsigned int* qp = sq + i * 17;
        const unsigned int* kp = sk + j * 17;
        float dot = 0.f;
#pragma unroll
        for (int u = 0; u < 16; u++) {
            unsigned int a = qp[u], b = kp[u];
            dot += b2f(a) * b2f(b) + b2f(a >> 16) * b2f(b >> 16);
        }
        int ih = i / 7, iw2 = i - ih * 7, jh = j / 7, jw2 = j - jh * 7;
        int idx = (ih - jh + 6) * 13 + (iw2 - jw2 + 6);
        ssc[e] = dot * 5.65685424949238f + table[idx * 4 + h];
    }
    __syncthreads();

    if (tid < 49) {
        float* row = ssc + tid * 49;
        float mx = -1e30f;
        for (int j = 0; j < 49; j++) mx = fmaxf(mx, row[j]);
        float sum = 0.f;
        for (int j = 0; j < 49; j++) { float p = __expf(row[j] - mx); row[j] = p; sum += p; }
        float inv = 1.f / sum;
        for (int j = 0; j < 49; j++) row[j] *= inv;
    }
    __syncthreads();

    unsigned int* outu = (unsigned int*)out;
    for (int e = tid; e < 784; e += 256) {
        int i = e >> 4, dp = e & 15;
        const float* pr = ssc + i * 49;
        float a0 = 0.f, a1 = 0.f;
        for (int j = 0; j < 49; j++) {
            float p = pr[j];
            unsigned int vv = sv[j * 17 + dp];
            a0 += p * b2f(vv);
            a1 += p * b2f(vv >> 16);
        }
        outu[(size_t)(w * 49 + i) * 64 + h * 16 + dp] =
            (unsigned int)f2b(a0) | ((unsigned int)f2b(a1) << 16);
    }
}

// ===========================================================================
// Grid attention v5 (32x32, N=1024). 64-key tiles. Bias enters as the MFMA
// C-operand via one unaligned-float4 L1 load per chunk (per-head contiguous
// pre-scaled table in tp) -- no LDS bias, no per-element fma. Frozen-max
// softmax: row max from tile 0 only (exact up to uniform scaling); l
// accumulated per-lane, reduced once at the end. No per-tile shfls.
// LDS 18.9 KB; conflict-free staging from v4.
// ===========================================================================
__global__ __launch_bounds__(256) void attn_grid32(const unsigned short* __restrict__ qkv,
                                                   const float* __restrict__ tp,
                                                   unsigned short* __restrict__ out) {
    __shared__ __align__(16) unsigned short sK[64][40];
    __shared__ __align__(16) unsigned short sVt[32][72];     // [dim][pos]
    __shared__ __align__(16) unsigned short plds[4][16][72]; // [wave][qrow][pos]
    const int tid = threadIdx.x;
    const int lane = tid & 63;
    const int wid = tid >> 6;
    const int b = blockIdx.x;                 // 49*4*16 = 3136
    const int w = b >> 6;
    const int h = (b >> 4) & 3;
    const int qb = b & 15;
    const int q0 = qb * 64 + wid * 16;
    const int c = lane & 15;
    const int g = lane >> 4;
    const size_t base = (size_t)w * 1024 * 384;
    const float scale2 = 5.65685424949238f * 1.4426950408889634f;  // sqrt(32)*log2(e)

    Frag qf;                                   // A-frag: Q[m=c][k=g*8..+7]
    qf.u4 = *(const uint4*)(qkv + base + (size_t)(q0 + c) * 384 + h * 32 + g * 8);

    // bias base for this lane: rows q0+g*4..+3 share ih; idx(rr) = base + rr
    const int qrow0 = q0 + g * 4;
    const float* tpl = tp + h * 3972 + ((qrow0 >> 5) + 31) * 63 + (qrow0 & 31) + 31 - c;

    float m_[4], l_[4];
    f32x4 o0 = {0.f, 0.f, 0.f, 0.f}, o1 = {0.f, 0.f, 0.f, 0.f};
#pragma unroll
    for (int rr = 0; rr < 4; rr++) { m_[rr] = 0.f; l_[rr] = 0.f; }

    // staging: key = lane, dim group = 8*wid (wave-uniform)
    const int skey = lane;
    const int sd = wid * 8;
    const int vpos = 4 * (skey & 15) + (skey >> 4);   // pos(k) = 4c + ch
    const unsigned short* kgp = qkv + base + 128 + h * 32 + sd;
    const unsigned short* vgp = qkv + base + 256 + h * 32 + sd;

    for (int jc = 0; jc < 1024; jc += 64) {
        __syncthreads();                       // prev tile's K/V reads done
        size_t roff = (size_t)(jc + skey) * 384;
        *(uint4*)(&sK[skey][sd]) = *(const uint4*)(kgp + roff);
        Frag vv;
        vv.u4 = *(const uint4*)(vgp + roff);
#pragma unroll
        for (int z = 0; z < 8; ++z) sVt[sd + z][vpos] = vv.s[z];  // conflict-free
        __syncthreads();

        // QK^T: 4 chunks of 16 keys, bias as C operand (global L1 float4)
        const float* tpj = tpl - (jc >> 5) * 63;
        f32x4 s4[4];
#pragma unroll
        for (int ch = 0; ch < 4; ++ch) {
            f32x4 cb = (f32x4)(*(const f32x4u*)(tpj - (ch >> 1) * 63 - (ch & 1) * 16));
            Frag kf;
            kf.u4 = *(const uint4*)(&sK[ch * 16 + c][g * 8]);
            s4[ch] = __builtin_amdgcn_mfma_f32_16x16x32_bf16(qf.b, kf.b, cb, 0, 0, 0);
        }
        // frozen-max softmax (log2 domain); no per-tile reductions
#pragma unroll
        for (int rr = 0; rr < 4; ++rr) {
            float v0 = s4[0][rr] * scale2;
            float v1 = s4[1][rr] * scale2;
            float v2 = s4[2][rr] * scale2;
            float v3 = s4[3][rr] * scale2;
            if (jc == 0) {
                float cm = fmaxf(fmaxf(v0, v1), fmaxf(v2, v3));
#pragma unroll
                for (int off = 1; off < 16; off <<= 1) cm = fmaxf(cm, __shfl_xor(cm, off, 64));
                m_[rr] = cm;
            }
            float mn = m_[rr];
            float p0 = exp2f(v0 - mn);
            float p1 = exp2f(v1 - mn);
            float p2 = exp2f(v2 - mn);
            float p3 = exp2f(v3 - mn);
            l_[rr] += (p0 + p1) + (p2 + p3);
            unsigned int* prow = (unsigned int*)(&plds[wid][g * 4 + rr][c * 4]);
            prow[0] = (unsigned int)f2b(p0) | ((unsigned int)f2b(p1) << 16);
            prow[1] = (unsigned int)f2b(p2) | ((unsigned int)f2b(p3) << 16);
        }
        // PV over positions: 2 chunks of 32; all operands b128; plds per-wave
#pragma unroll
        for (int ch2 = 0; ch2 < 2; ++ch2) {
            Frag pf, vf0, vf1;
            pf.u4 = *(const uint4*)(&plds[wid][c][ch2 * 32 + g * 8]);
            vf0.u4 = *(const uint4*)(&sVt[c][ch2 * 32 + g * 8]);
            vf1.u4 = *(const uint4*)(&sVt[16 + c][ch2 * 32 + g * 8]);
            o0 = __builtin_amdgcn_mfma_f32_16x16x32_bf16(pf.b, vf0.b, o0, 0, 0, 0);
            o1 = __builtin_amdgcn_mfma_f32_16x16x32_bf16(pf.b, vf1.b, o1, 0, 0, 0);
        }
    }
#pragma unroll
    for (int rr = 0; rr < 4; rr++) {
        float ls = l_[rr];
#pragma unroll
        for (int off = 1; off < 16; off <<= 1) ls += __shfl_xor(ls, off, 64);
        float inv = 1.0f / ls;
        int row = q0 + g * 4 + rr;
        size_t ob = (size_t)(w * 1024 + row) * 128 + h * 32;
        out[ob + c] = f2b(o0[rr] * inv);
        out[ob + 16 + c] = f2b(o1[rr] * inv);
    }
}

// LayerNorm on fp32 input; writes bf16 (GEMM input) + fp32 (MLP shortcut).
__global__ __launch_bounds__(256) void ln_f(const float* __restrict__ in,
                                            const float* __restrict__ gam,
                                            const float* __restrict__ bet,
                                            unsigned short* __restrict__ outb,
                                            float* __restrict__ outf) {
    int token = blockIdx.x * 4 + (threadIdx.x >> 6);
    int lane = threadIdx.x & 63;
    float2 v = ((const float2*)in)[(size_t)token * 64 + lane];
    float s = v.x + v.y, s2 = v.x * v.x + v.y * v.y;
#pragma unroll
    for (int off = 1; off < 64; off <<= 1) {
        s += __shfl_xor(s, off, 64);
        s2 += __shfl_xor(s2, off, 64);
    }
    float mean = s * (1.f / 128.f);
    float var = s2 * (1.f / 128.f) - mean * mean;
    float inv = rsqrtf(var + 1e-5f);
    float2 gv = ((const float2*)gam)[lane];
    float2 bv = ((const float2*)bet)[lane];
    float y0 = (v.x - mean) * inv * gv.x + bv.x;
    float y1 = (v.y - mean) * inv * gv.y + bv.y;
    ((unsigned int*)outb)[(size_t)token * 64 + lane] =
        (unsigned int)f2b(y0) | ((unsigned int)f2b(y1) << 16);
    ((float2*)outf)[(size_t)token * 64 + lane] = make_float2(y0, y1);
}

// unbind(7)+transpose+partition(32): fp32 ya -> bf16 xb + fp32 xbf
__global__ __launch_bounds__(256) void remap_ab_f(const float* __restrict__ ya,
                                                  unsigned short* __restrict__ xb,
                                                  float* __restrict__ xbf) {
    int t = blockIdx.x * 256 + threadIdx.x;
    int c2 = t & 127;
    int tok = (t >> 7) & 1023;
    int W2 = t >> 17;
    int P = tok >> 5, Q = tok & 31;
    int I = W2 / 7, J = W2 - I * 7;
    int y = I * 32 + P, x2 = J * 32 + Q;
    int f = y * 28672 + x2 * 128 + c2;
    int c = f / 50176;
    int rm = f - c * 50176;
    int i = rm / 1568;
    int r2 = rm - i * 1568;
    int p = r2 / 224;
    int r3 = r2 - p * 224;
    int q = r3 >> 5, j = r3 & 31;
    float val = ya[((size_t)((i * 32 + j) * 49 + p * 7 + q)) * 128 + c];
    xb[t] = f2b(val);
    xbf[t] = val;
}

// unbind(32)+final transpose: fp32 yb -> fp32 out[1,128,224,224]
__global__ __launch_bounds__(256) void remap_out_f(const float* __restrict__ yb,
                                                   float* __restrict__ out) {
    int t = blockIdx.x * 256 + threadIdx.x;
    int c2 = t / 50176;
    int rem = t - c2 * 50176;
    int y = rem / 224;
    int x2 = rem - y * 224;
    int g = y * 28672 + x2 * 128 + c2;
    int c = g / 50176;
    int r = g - c * 50176;
    int I = r / 7168;
    int r2 = r - I * 7168;
    int P = r2 / 224;
    int r3 = r2 - P * 224;
    int Q = r3 / 7, J = r3 - Q * 7;
    out[t] = yb[((size_t)((I * 7 + J) * 1024 + P * 32 + Q)) * 128 + c];
}

// ===========================================================================
// FALLBACK PATH (proven round-7 scalar kernels; used if ws_size too small)
// ===========================================================================
__global__ __launch_bounds__(256) void remap_ab_s(const unsigned short* __restrict__ ya,
                                                  unsigned short* __restrict__ xb) {
    int t = blockIdx.x * 256 + threadIdx.x;
    int c2 = t & 127;
    int tok = (t >> 7) & 1023;
    int W2 = t >> 17;
    int P = tok >> 5, Q = tok & 31;
    int I = W2 / 7, J = W2 - I * 7;
    int y = I * 32 + P, x2 = J * 32 + Q;
    int f = y * 28672 + x2 * 128 + c2;
    int c = f / 50176;
    int rm = f - c * 50176;
    int i = rm / 1568;
    int r2 = rm - i * 1568;
    int p = r2 / 224;
    int r3 = r2 - p * 224;
    int q = r3 >> 5, j = r3 & 31;
    xb[t] = ya[((size_t)((i * 32 + j) * 49 + p * 7 + q)) * 128 + c];
}
__global__ __launch_bounds__(256) void remap_out_s(const unsigned short* __restrict__ yb,
                                                   float* __restrict__ out) {
    int t = blockIdx.x * 256 + threadIdx.x;
    int c2 = t / 50176;
    int rem = t - c2 * 50176;
    int y = rem / 224;
    int x2 = rem - y * 224;
    int g = y * 28672 + x2 * 128 + c2;
    int c = g / 50176;
    int r = g - c * 50176;
    int I = r / 7168;
    int r2 = r - I * 7168;
    int P = r2 / 224;
    int r3 = r2 - P * 224;
    int Q = r3 / 7, J = r3 - Q * 7;
    out[t] = b2f(yb[((size_t)((I * 7 + J) * 1024 + P * 32 + Q)) * 128 + c]);
}
__global__ __launch_bounds__(256) void gemm_w32(const unsigned short* __restrict__ X,
                                                const float* __restrict__ W,
                                                const float* __restrict__ bias,
                                                const unsigned short* __restrict__ res,
                                                unsigned short* __restrict__ Y,
                                                int M, int N, int K) {
    long long t = (long long)blockIdx.x * 256 + threadIdx.x;
    if (t >= (long long)M * N) return;
    int m = (int)(t / N);
    int n = (int)(t - (long long)m * N);
    const unsigned short* xr = X + (size_t)m * K;
    const float* wr = W + (size_t)n * K;
    float acc = bias ? bias[n] : 0.f;
    for (int k = 0; k < K; ++k) acc += b2f(xr[k]) * wr[k];
    if (res) acc += b2f(res[t]);
    Y[t] = f2b(acc);
}
__global__ __launch_bounds__(256) void attn_block7_fused(const unsigned short* __restrict__ xa,
                                                         const float* __restrict__ qw,
                                                         const float* __restrict__ table,
                                                         unsigned short* __restrict__ out) {
    __shared__ unsigned short sx[49 * 128];
    __shared__ float sq[49 * 32], sk[49 * 32], sv[49 * 32];
    __shared__ float ssc[49 * 49];
    const int bx = blockIdx.x;
    const int w = bx >> 2, h = bx & 3;
    const int tid = threadIdx.x;
    for (int u = tid; u < 6272; u += 256) sx[u] = xa[(size_t)(w * 49) * 128 + u];
    __syncthreads();
    for (int e = tid; e < 4704; e += 256) {
        int which = e / 1568;
        int rem = e - which * 1568;
        int n = rem >> 5, d = rem & 31;
        const float* wr = qw + (size_t)(which * 128 + h * 32 + d) * 128;
        const unsigned short* xr = sx + n * 128;
        float acc = 0.f;
        for (int k = 0; k < 128; ++k) acc += b2f(xr[k]) * wr[k];
        if (which == 0) sq[n * 32 + d] = acc;
        else if (which == 1) sk[n * 32 + d] = acc;
        else sv[n * 32 + d] = acc;
    }
    __syncthreads();
    for (int e = tid; e < 2401; e += 256) {
        int i = e / 49, j = e - i * 49;
        float dot = 0.f;
        for (int d = 0; d < 32; ++d) dot += sq[i * 32 + d] * sk[j * 32 + d];
        int ih = i / 7, iw2 = i - ih * 7, jh = j / 7, jw2 = j - jh * 7;
        int idx = (ih - jh + 6) * 13 + (iw2 - jw2 + 6);
        ssc[e] = dot * 5.65685424949238f + table[idx * 4 + h];
    }
    __syncthreads();
    if (tid < 49) {
        float* row = ssc + tid * 49;
        float mx = -1e30f;
        for (int j = 0; j < 49; j++) mx = fmaxf(mx, row[j]);
        float sum = 0.f;
        for (int j = 0; j < 49; j++) { float p = __expf(row[j] - mx); row[j] = p; sum += p; }
        float inv = 1.f / sum;
        for (int j = 0; j < 49; j++) row[j] *= inv;
    }
    __syncthreads();
    for (int e = tid; e < 1568; e += 256) {
        int i = e >> 5, d = e & 31;
        const float* pr = ssc + i * 49;
        float a = 0.f;
        for (int j = 0; j < 49; j++) a += pr[j] * sv[j * 32 + d];
        out[(size_t)(w * 49 + i) * 128 + h * 32 + d] = f2b(a);
    }
}
__global__ __launch_bounds__(256) void kv_head(const unsigned short* __restrict__ xa,
                                               const float* __restrict__ qw,
                                               int h,
                                               unsigned short* __restrict__ kvh) {
    int t = blockIdx.x * 256 + threadIdx.x;
    int tok = t >> 6, e = t & 63;
    int which = (e < 32) ? 1 : 2;
    int d = e & 31;
    const float* wr = qw + (size_t)(which * 128 + h * 32 + d) * 128;
    const unsigned short* xr = xa + (size_t)tok * 128;
    float acc = 0.f;
    for (int k = 0; k < 128; ++k) acc += b2f(xr[k]) * wr[k];
    kvh[t] = f2b(acc);
}
__global__ __launch_bounds__(256) void attn_grid_head(const unsigned short* __restrict__ xa,
                                                      const unsigned short* __restrict__ kvh,
                                                      const float* __restrict__ qw,
                                                      const float* __restrict__ table,
                                                      int h,
                                                      unsigned short* __restrict__ out) {
    __shared__ float sq[32];
    __shared__ float ss[1024];
    __shared__ float red[256];
    __shared__ float pvp[256];
    const int w = blockIdx.x >> 4;
    const int qg = blockIdx.x & 15;
    const int tid = threadIdx.x;
    const float scale = 5.65685424949238f;
    for (int qq = 0; qq < 64; ++qq) {
        const int qi = qg * 64 + qq;
        const int tok = w * 1024 + qi;
        if (tid < 32) {
            const float* wr = qw + (size_t)(h * 32 + tid) * 128;
            const unsigned short* xr = xa + (size_t)tok * 128;
            float acc = 0.f;
            for (int k = 0; k < 128; ++k) acc += b2f(xr[k]) * wr[k];
            sq[tid] = acc;
        }
        __syncthreads();
        const int ihq = qi >> 5, iwq = qi & 31;
        for (int k = tid; k < 1024; k += 256) {
            const unsigned short* kp = kvh + (size_t)(w * 1024 + k) * 64;
            float dot = 0.f;
            for (int d = 0; d < 32; ++d) dot += sq[d] * b2f(kp[d]);
            int jh2 = k >> 5, jw2 = k & 31;
            int idx = (ihq - jh2 + 31) * 63 + (iwq - jw2 + 31);
            ss[k] = dot * scale + table[idx * 4 + h];
        }
        __syncthreads();
        float m = fmaxf(fmaxf(ss[tid], ss[tid + 256]), fmaxf(ss[tid + 512], ss[tid + 768]));
        red[tid] = m;
        __syncthreads();
        for (int s = 128; s > 0; s >>= 1) {
            if (tid < s) red[tid] = fmaxf(red[tid], red[tid + s]);
            __syncthreads();
        }
        m = red[0];
        __syncthreads();
        float ps = 0.f;
        for (int k = tid; k < 1024; k += 256) {
            float p = __expf(ss[k] - m);
            ss[k] = p;
            ps += p;
        }
        red[tid] = ps;
        __syncthreads();
        for (int s = 128; s > 0; s >>= 1) {
            if (tid < s) red[tid] += red[tid + s];
            __syncthreads();
        }
        float l = red[0];
        int kc = tid >> 5, d = tid & 31;
        float a = 0.f;
        const unsigned short* vbase = kvh + (size_t)(w * 1024) * 64 + 32 + d;
        for (int k = kc * 128; k < kc * 128 + 128; ++k) a += ss[k] * b2f(vbase[(size_t)k * 64]);
        pvp[tid] = a;
        __syncthreads();
        if (tid < 32) {
            float o = 0.f;
            for (int c2 = 0; c2 < 8; ++c2) o += pvp[c2 * 32 + tid];
            out[(size_t)tok * 128 + h * 32 + tid] = f2b(o / l);
        }
        __syncthreads();
    }
}
__global__ __launch_bounds__(256) void mlp_fused(const unsigned short* __restrict__ xin,
                                                 const float* __restrict__ fc1w,
                                                 const float* __restrict__ fc1b,
                                                 const float* __restrict__ fc2w,
                                                 const float* __restrict__ fc2b,
                                                 unsigned short* __restrict__ out) {
    __shared__ float sxr[128];
    __shared__ float sh[512];
    const int tok = blockIdx.x;
    const int tid = threadIdx.x;
    if (tid < 128) sxr[tid] = b2f(xin[(size_t)tok * 128 + tid]);
    __syncthreads();
    for (int hh = tid; hh < 512; hh += 256) {
        const float* wr = fc1w + (size_t)hh * 128;
        float acc = fc1b[hh];
        for (int k = 0; k < 128; ++k) acc += sxr[k] * wr[k];
        sh[hh] = acc;
    }
    __syncthreads();
    if (tid < 128) {
        const float* wr = fc2w + (size_t)tid * 512;
        float acc = fc2b[tid];
        for (int k = 0; k < 512; ++k) acc += sh[k] * wr[k];
        out[(size_t)tok * 128 + tid] = f2b(acc + sxr[tid]);
    }
}
__global__ __launch_bounds__(256) void ln_k(const unsigned short* __restrict__ in,
                                            const float* __restrict__ gam,
                                            const float* __restrict__ bet,
                                            unsigned short* __restrict__ out) {
    int token = blockIdx.x * 4 + (threadIdx.x >> 6);
    int lane = threadIdx.x & 63;
    const unsigned int* row = (const unsigned int*)in + (size_t)token * 64;
    unsigned int v = row[lane];
    float x0 = b2f(v), x1 = b2f(v >> 16);
    float s = x0 + x1, s2 = x0 * x0 + x1 * x1;
#pragma unroll
    for (int off = 1; off < 64; off <<= 1) {
        s += __shfl_xor(s, off, 64);
        s2 += __shfl_xor(s2, off, 64);
    }
    float mean = s * (1.f / 128.f);
    float var = s2 * (1.f / 128.f) - mean * mean;
    float inv = rsqrtf(var + 1e-5f);
    float2 gv = ((const float2*)gam)[lane];
    float2 bv = ((const float2*)bet)[lane];
    float y0 = (x0 - mean) * inv * gv.x + bv.x;
    float y1 = (x1 - mean) * inv * gv.y + bv.y;
    ((unsigned int*)out)[(size_t)token * 64 + lane] =
        (unsigned int)f2b(y0) | ((unsigned int)f2b(y1) << 16);
}

// ===========================================================================
extern "C" void kernel_launch(void* const* d_in, const int* in_sizes, int n_in,
                              void* d_out, int out_size, void* d_ws, size_t ws_size,
                              hipStream_t stream) {
    (void)in_sizes; (void)n_in; (void)out_size;
    const float* x = (const float*)d_in[0];
    unsigned short* ws = (unsigned short*)d_ws;
    const int M = 50176;
    dim3 blk(256);
    #define F32(i) ((const float*)d_in[i])

    if (ws_size >= 117178368ull) {
        // ---------------- FAST PATH (MFMA, split weights) ----------------
        unsigned short* WHI = ws;
        unsigned short* WLO = ws + 393216;
        unsigned short* XA  = ws + 786432;
        unsigned short* AT  = ws + 7208960;
        unsigned short* Y2  = ws + 13631488;
        float*          R1  = (float*)(ws + 20054016);
        unsigned short* BIG = ws + 32899072;
        float*          Yf  = (float*)d_out;          // Y1f scratch
        float*          YOB = (float*)XA;             // stage-B fp32 out (XA∪AT)
        float*          TP  = (float*)d_out + 6400000; // grid-bias table (dead window)

        WPtrs wp = {F32(2), F32(3), F32(7), F32(9), F32(12), F32(13), F32(17), F32(19)};
        const size_t oqkv = 0, oproj = 49152, ofc1 = 65536, ofc2 = 131072;
        const size_t goff = 196608;

        conv_w2<<<1536, blk, 0, stream>>>(wp, WHI, WLO);
        gather_in<<<25088, blk, 0, stream>>>(x, XA);

        // ---- stage A ----
        gemm_bt<<<dim3(6, 392), blk, 0, stream>>>(XA, WHI + oqkv, WLO + oqkv, nullptr,
                                                  nullptr, nullptr, BIG, nullptr, M, 384, 128);
        attn_block7<<<4096, blk, 0, stream>>>(BIG, F32(1), AT);
        gemm_bt<<<dim3(2, 392), blk, 0, stream>>>(AT, WHI + oproj, WLO + oproj, F32(4),
                                                  nullptr, x, nullptr, Yf, M, 128, 128);
        ln_f<<<12544, blk, 0, stream>>>(Yf, F32(5), F32(6), Y2, R1);
        gemm_bt<<<dim3(8, 392), blk, 0, stream>>>(Y2, WHI + ofc1, WLO + ofc1, F32(8),
                                                  nullptr, nullptr, BIG, nullptr, M, 512, 128);
        gemm_bt<<<dim3(2, 392), blk, 0, stream>>>(BIG, WHI + ofc2, WLO + ofc2, F32(10),
                                                  R1, nullptr, nullptr, Yf, M, 128, 512);
        remap_ab_f<<<25088, blk, 0, stream>>>(Yf, XA, R1);

        // ---- stage B ----
        conv_bias<<<63, blk, 0, stream>>>(F32(11), TP);  // d_out tail is dead here
        gemm_bt<<<dim3(6, 392), blk, 0, stream>>>(XA, WHI + goff + oqkv, WLO + goff + oqkv,
                                                  nullptr, nullptr, nullptr, BIG, nullptr, M, 384, 128);
        attn_grid32<<<3136, blk, 0, stream>>>(BIG, TP, AT);
        gemm_bt<<<dim3(2, 392), blk, 0, stream>>>(AT, WHI + goff + oproj, WLO + goff + oproj,
                                                  F32(14), R1, nullptr, nullptr, Yf, M, 128, 128);
        ln_f<<<12544, blk, 0, stream>>>(Yf, F32(15), F32(16), Y2, R1);
        gemm_bt<<<dim3(8, 392), blk, 0, stream>>>(Y2, WHI + goff + ofc1, WLO + goff + ofc1,
                                                  F32(18), nullptr, nullptr, BIG, nullptr, M, 512, 128);
        gemm_bt<<<dim3(2, 392), blk, 0, stream>>>(BIG, WHI + goff + ofc2, WLO + goff + ofc2,
                                                  F32(20), R1, nullptr, nullptr, YOB, M, 128, 512);
        remap_out_f<<<25088, blk, 0, stream>>>(YOB, (float*)d_out);
    } else {
        // ---------------- FALLBACK (proven round-7 scalar path) ----------------
        unsigned short* XA  = ws;
        unsigned short* AT  = XA + 6422528;
        unsigned short* KVh = AT + 6422528;
        unsigned short* Yd  = (unsigned short*)d_out;

        gather_in<<<25088, blk, 0, stream>>>(x, XA);
        attn_block7_fused<<<4096, blk, 0, stream>>>(XA, F32(2), F32(1), AT);
        gemm_w32<<<25088, blk, 0, stream>>>(AT, F32(3), F32(4), XA, Yd, M, 128, 128);
        ln_k<<<12544, blk, 0, stream>>>(Yd, F32(5), F32(6), Yd);
        mlp_fused<<<50176, blk, 0, stream>>>(Yd, F32(7), F32(8), F32(9), F32(10), AT);
        remap_ab_s<<<25088, blk, 0, stream>>>(AT, XA);
        for (int h = 0; h < 4; ++h) {
            kv_head<<<12544, blk, 0, stream>>>(XA, F32(12), h, KVh);
            attn_grid_head<<<784, blk, 0, stream>>>(XA, KVh, F32(12), F32(11), h, AT);
        }
        gemm_w32<<<25088, blk, 0, stream>>>(AT, F32(13), F32(14), XA, Yd, M, 128, 128);
        ln_k<<<12544, blk, 0, stream>>>(Yd, F32(15), F32(16), Yd);
        mlp_fused<<<50176, blk, 0, stream>>>(Yd, F32(17), F32(18), F32(19), F32(20), AT);
        remap_out_s<<<25088, blk, 0, stream>>>(AT, (float*)d_out);
    }
    #undef F32
}

// Round 15
// 693.960 us; speedup vs baseline: 1.5215x; 1.3429x over previous
//
#include <hip/hip_runtime.h>

typedef __bf16 bf16x8 __attribute__((ext_vector_type(8)));
typedef float f32x4 __attribute__((ext_vector_type(4)));
typedef float f32x4u __attribute__((ext_vector_type(4), aligned(4)));

union Frag {
    uint4 u4;
    bf16x8 b;
    unsigned short s[8];
};

__device__ __forceinline__ float b2f(unsigned int u) {
    return __uint_as_float((u & 0xffffu) << 16);
}
__device__ __forceinline__ unsigned short f2b(float f) {
    unsigned int x = __float_as_uint(f);
    unsigned int r = x + 0x7fffu + ((x >> 16) & 1u);  // RNE
    return (unsigned short)(r >> 16);
}

// ===========================================================================
// Weight conversion: fp32 -> bf16 hi + bf16 lo (w ≈ hi + lo to ~2^-18 rel)
// ===========================================================================
struct WPtrs {
    const float *bqkv, *bproj, *bfc1, *bfc2, *gqkv, *gproj, *gfc1, *gfc2;
};
__global__ __launch_bounds__(256) void conv_w2(WPtrs p, unsigned short* __restrict__ hi,
                                               unsigned short* __restrict__ lo) {
    int t = blockIdx.x * 256 + threadIdx.x;      // 393216 total
    float v;
    if (t < 49152)       v = p.bqkv[t];
    else if (t < 65536)  v = p.bproj[t - 49152];
    else if (t < 131072) v = p.bfc1[t - 65536];
    else if (t < 196608) v = p.bfc2[t - 131072];
    else if (t < 245760) v = p.gqkv[t - 196608];
    else if (t < 262144) v = p.gproj[t - 245760];
    else if (t < 327680) v = p.gfc1[t - 262144];
    else                 v = p.gfc2[t - 327680];
    unsigned short h = f2b(v);
    hi[t] = h;
    lo[t] = f2b(v - b2f(h));
}

// Per-head contiguous grid-bias table, pre-scaled by 1/sqrt(32) (C-operand).
__global__ __launch_bounds__(256) void conv_bias(const float* __restrict__ table,
                                                 float* __restrict__ tp) {
    int t = blockIdx.x * 256 + threadIdx.x;      // 15876 total
    if (t >= 15876) return;
    int h = t / 3969;
    int idx = t - h * 3969;
    tp[h * 3972 + idx] = table[idx * 4 + h] * 0.17677669529663689f;
}

// window_partition(x,7,7): fp32 x[1,128,224,224] -> bf16 xa[win*49+n][c]
__global__ __launch_bounds__(256) void gather_in(const float* __restrict__ x,
                                                 unsigned short* __restrict__ xa) {
    int t = blockIdx.x * 256 + threadIdx.x;       // 6422528
    int c = t & 127;
    int wn = t >> 7;
    int n = wn % 49;
    int w = wn / 49;
    int i = w >> 5, j = w & 31;
    int p = n / 7, q = n - p * 7;
    xa[t] = f2b(x[(size_t)c * 50176 + (i * 7 + p) * 224 + (j * 7 + q)]);
}

// ===========================================================================
// MFMA GEMM v2: split (hi+lo) weights, B-strip staged in LDS per K-tile.
// Block = 128 rows x 64 cols; B (64 cols x 128 K, hi+lo) loaded once per
// K-tile cooperatively (pitch 138: <=2-way banks on write and read); inner
// loop: A from global (2 b128/wave/chunk), B via ds_read_b128.
// ===========================================================================
__global__ __launch_bounds__(256) void gemm_bt(const unsigned short* __restrict__ X,
                                               const unsigned short* __restrict__ Whi,
                                               const unsigned short* __restrict__ Wlo,
                                               const float* __restrict__ bias,
                                               const float* __restrict__ resf,
                                               const float* __restrict__ resx,
                                               unsigned short* __restrict__ Yb,
                                               float* __restrict__ Yf,
                                               int M, int N, int K) {
    __shared__ __align__(16) unsigned short sBh[64][138];
    __shared__ __align__(16) unsigned short sBl[64][138];
    const int tid = threadIdx.x;
    const int lane = tid & 63;
    const int wid = tid >> 6;
    const int m0 = blockIdx.y * 128 + wid * 32;
    const int n0 = blockIdx.x * 64;
    const int r = lane & 15, g = lane >> 4;

    f32x4 acc[2][4];
#pragma unroll
    for (int i = 0; i < 2; i++)
#pragma unroll
        for (int j = 0; j < 4; j++) acc[i][j] = (f32x4){0.f, 0.f, 0.f, 0.f};

    const unsigned short* xa0 = X + (size_t)(m0 + r) * K + g * 8;
    const unsigned short* xa1 = X + (size_t)(m0 + 16 + r) * K + g * 8;

    const int bc = tid >> 2;          // 0..63: column within strip
    const int bk = (tid & 3) * 32;    // 0,32,64,96: k-offset within tile
    const size_t wrow = (size_t)(n0 + bc) * K + bk;

    for (int kt = 0; kt < K; kt += 128) {
        __syncthreads();              // previous tile's B reads done
        const unsigned short* sh = Whi + wrow + kt;
        const unsigned short* sl = Wlo + wrow + kt;
        *(uint4*)(&sBh[bc][bk]) = *(const uint4*)(sh);
        *(uint4*)(&sBh[bc][bk + 8]) = *(const uint4*)(sh + 8);
        *(uint4*)(&sBh[bc][bk + 16]) = *(const uint4*)(sh + 16);
        *(uint4*)(&sBh[bc][bk + 24]) = *(const uint4*)(sh + 24);
        *(uint4*)(&sBl[bc][bk]) = *(const uint4*)(sl);
        *(uint4*)(&sBl[bc][bk + 8]) = *(const uint4*)(sl + 8);
        *(uint4*)(&sBl[bc][bk + 16]) = *(const uint4*)(sl + 16);
        *(uint4*)(&sBl[bc][bk + 24]) = *(const uint4*)(sl + 24);
        __syncthreads();

#pragma unroll
        for (int kc = 0; kc < 128; kc += 32) {
            Frag a0, a1;
            a0.u4 = *(const uint4*)(xa0 + kt + kc);
            a1.u4 = *(const uint4*)(xa1 + kt + kc);
#pragma unroll
            for (int j = 0; j < 4; j++) {
                Frag bh, bl;
                bh.u4 = *(const uint4*)(&sBh[j * 16 + r][kc + g * 8]);
                bl.u4 = *(const uint4*)(&sBl[j * 16 + r][kc + g * 8]);
                acc[0][j] = __builtin_amdgcn_mfma_f32_16x16x32_bf16(a0.b, bh.b, acc[0][j], 0, 0, 0);
                acc[0][j] = __builtin_amdgcn_mfma_f32_16x16x32_bf16(a0.b, bl.b, acc[0][j], 0, 0, 0);
                acc[1][j] = __builtin_amdgcn_mfma_f32_16x16x32_bf16(a1.b, bh.b, acc[1][j], 0, 0, 0);
                acc[1][j] = __builtin_amdgcn_mfma_f32_16x16x32_bf16(a1.b, bl.b, acc[1][j], 0, 0, 0);
            }
        }
    }
#pragma unroll
    for (int i = 0; i < 2; i++) {
#pragma unroll
        for (int j = 0; j < 4; j++) {
            int col = n0 + j * 16 + r;
            float bia = bias ? bias[col] : 0.f;
#pragma unroll
            for (int rr = 0; rr < 4; rr++) {
                int rowi = m0 + i * 16 + g * 4 + rr;
                size_t idx = (size_t)rowi * N + col;
                float v = acc[i][j][rr] + bia;
                if (resf) v += resf[idx];
                if (resx) {
                    int w = rowi / 49, n = rowi - w * 49;
                    int ii = w >> 5, jj = w & 31;
                    int p = n / 7, q = n - p * 7;
                    v += resx[(size_t)col * 50176 + (ii * 7 + p) * 224 + (jj * 7 + q)];
                }
                if (Yb) Yb[idx] = f2b(v);
                if (Yf) Yf[idx] = v;
            }
        }
    }
}

// Block attention (7x7, N=49). One block per (window, head). QKV bf16 in.
__global__ __launch_bounds__(256) void attn_block7(const unsigned short* __restrict__ qkv,
                                                   const float* __restrict__ table,
                                                   unsigned short* __restrict__ out) {
    __shared__ __align__(16) unsigned int sq[49 * 17], sk[49 * 17], sv[49 * 17];
    __shared__ float ssc[49 * 49];
    const int bx = blockIdx.x;
    const int w = bx >> 2, h = bx & 3;
    const int tid = threadIdx.x;
    const unsigned int* qsrc = (const unsigned int*)qkv;

    for (int u = tid; u < 784; u += 256) {
        int i = u >> 4, du = u & 15;
        size_t rb = (size_t)(w * 49 + i) * 192 + h * 16 + du;
        sq[i * 17 + du] = qsrc[rb];
        sk[i * 17 + du] = qsrc[rb + 64];
        sv[i * 17 + du] = qsrc[rb + 128];
    }
    __syncthreads();

    for (int e = tid; e < 2401; e += 256) {
        int i = e / 49, j = e - i * 49;
        const unsigned int* qp = sq + i * 17;
        const unsigned int* kp = sk + j * 17;
        float dot = 0.f;
#pragma unroll
        for (int u = 0; u < 16; u++) {
            unsigned int a = qp[u], b = kp[u];
            dot += b2f(a) * b2f(b) + b2f(a >> 16) * b2f(b >> 16);
        }
        int ih = i / 7, iw2 = i - ih * 7, jh = j / 7, jw2 = j - jh * 7;
        int idx = (ih - jh + 6) * 13 + (iw2 - jw2 + 6);
        ssc[e] = dot * 5.65685424949238f + table[idx * 4 + h];
    }
    __syncthreads();

    if (tid < 49) {
        float* row = ssc + tid * 49;
        float mx = -1e30f;
        for (int j = 0; j < 49; j++) mx = fmaxf(mx, row[j]);
        float sum = 0.f;
        for (int j = 0; j < 49; j++) { float p = __expf(row[j] - mx); row[j] = p; sum += p; }
        float inv = 1.f / sum;
        for (int j = 0; j < 49; j++) row[j] *= inv;
    }
    __syncthreads();

    unsigned int* outu = (unsigned int*)out;
    for (int e = tid; e < 784; e += 256) {
        int i = e >> 4, dp = e & 15;
        const float* pr = ssc + i * 49;
        float a0 = 0.f, a1 = 0.f;
        for (int j = 0; j < 49; j++) {
            float p = pr[j];
            unsigned int vv = sv[j * 17 + dp];
            a0 += p * b2f(vv);
            a1 += p * b2f(vv >> 16);
        }
        outu[(size_t)(w * 49 + i) * 64 + h * 16 + dp] =
            (unsigned int)f2b(a0) | ((unsigned int)f2b(a1) << 16);
    }
}

// ===========================================================================
// Grid attention v5 (32x32, N=1024). 64-key tiles. Bias as MFMA C-operand
// (per-head contiguous pre-scaled table, L1 float4). Frozen-max softmax.
// ===========================================================================
__global__ __launch_bounds__(256) void attn_grid32(const unsigned short* __restrict__ qkv,
                                                   const float* __restrict__ tp,
                                                   unsigned short* __restrict__ out) {
    __shared__ __align__(16) unsigned short sK[64][40];
    __shared__ __align__(16) unsigned short sVt[32][72];     // [dim][pos]
    __shared__ __align__(16) unsigned short plds[4][16][72]; // [wave][qrow][pos]
    const int tid = threadIdx.x;
    const int lane = tid & 63;
    const int wid = tid >> 6;
    const int b = blockIdx.x;                 // 49*4*16 = 3136
    const int w = b >> 6;
    const int h = (b >> 4) & 3;
    const int qb = b & 15;
    const int q0 = qb * 64 + wid * 16;
    const int c = lane & 15;
    const int g = lane >> 4;
    const size_t base = (size_t)w * 1024 * 384;
    const float scale2 = 5.65685424949238f * 1.4426950408889634f;  // sqrt(32)*log2(e)

    Frag qf;                                   // A-frag: Q[m=c][k=g*8..+7]
    qf.u4 = *(const uint4*)(qkv + base + (size_t)(q0 + c) * 384 + h * 32 + g * 8);

    const int qrow0 = q0 + g * 4;
    const float* tpl = tp + h * 3972 + ((qrow0 >> 5) + 31) * 63 + (qrow0 & 31) + 31 - c;

    float m_[4], l_[4];
    f32x4 o0 = {0.f, 0.f, 0.f, 0.f}, o1 = {0.f, 0.f, 0.f, 0.f};
#pragma unroll
    for (int rr = 0; rr < 4; rr++) { m_[rr] = 0.f; l_[rr] = 0.f; }

    const int skey = lane;
    const int sd = wid * 8;
    const int vpos = 4 * (skey & 15) + (skey >> 4);   // pos(k) = 4c + ch
    const unsigned short* kgp = qkv + base + 128 + h * 32 + sd;
    const unsigned short* vgp = qkv + base + 256 + h * 32 + sd;

    for (int jc = 0; jc < 1024; jc += 64) {
        __syncthreads();
        size_t roff = (size_t)(jc + skey) * 384;
        *(uint4*)(&sK[skey][sd]) = *(const uint4*)(kgp + roff);
        Frag vv;
        vv.u4 = *(const uint4*)(vgp + roff);
#pragma unroll
        for (int z = 0; z < 8; ++z) sVt[sd + z][vpos] = vv.s[z];
        __syncthreads();

        const float* tpj = tpl - (jc >> 5) * 63;
        f32x4 s4[4];
#pragma unroll
        for (int ch = 0; ch < 4; ++ch) {
            f32x4 cb = (f32x4)(*(const f32x4u*)(tpj - (ch >> 1) * 63 - (ch & 1) * 16));
            Frag kf;
            kf.u4 = *(const uint4*)(&sK[ch * 16 + c][g * 8]);
            s4[ch] = __builtin_amdgcn_mfma_f32_16x16x32_bf16(qf.b, kf.b, cb, 0, 0, 0);
        }
#pragma unroll
        for (int rr = 0; rr < 4; ++rr) {
            float v0 = s4[0][rr] * scale2;
            float v1 = s4[1][rr] * scale2;
            float v2 = s4[2][rr] * scale2;
            float v3 = s4[3][rr] * scale2;
            if (jc == 0) {
                float cm = fmaxf(fmaxf(v0, v1), fmaxf(v2, v3));
#pragma unroll
                for (int off = 1; off < 16; off <<= 1) cm = fmaxf(cm, __shfl_xor(cm, off, 64));
                m_[rr] = cm;
            }
            float mn = m_[rr];
            float p0 = exp2f(v0 - mn);
            float p1 = exp2f(v1 - mn);
            float p2 = exp2f(v2 - mn);
            float p3 = exp2f(v3 - mn);
            l_[rr] += (p0 + p1) + (p2 + p3);
            unsigned int* prow = (unsigned int*)(&plds[wid][g * 4 + rr][c * 4]);
            prow[0] = (unsigned int)f2b(p0) | ((unsigned int)f2b(p1) << 16);
            prow[1] = (unsigned int)f2b(p2) | ((unsigned int)f2b(p3) << 16);
        }
#pragma unroll
        for (int ch2 = 0; ch2 < 2; ++ch2) {
            Frag pf, vf0, vf1;
            pf.u4 = *(const uint4*)(&plds[wid][c][ch2 * 32 + g * 8]);
            vf0.u4 = *(const uint4*)(&sVt[c][ch2 * 32 + g * 8]);
            vf1.u4 = *(const uint4*)(&sVt[16 + c][ch2 * 32 + g * 8]);
            o0 = __builtin_amdgcn_mfma_f32_16x16x32_bf16(pf.b, vf0.b, o0, 0, 0, 0);
            o1 = __builtin_amdgcn_mfma_f32_16x16x32_bf16(pf.b, vf1.b, o1, 0, 0, 0);
        }
    }
#pragma unroll
    for (int rr = 0; rr < 4; rr++) {
        float ls = l_[rr];
#pragma unroll
        for (int off = 1; off < 16; off <<= 1) ls += __shfl_xor(ls, off, 64);
        float inv = 1.0f / ls;
        int row = q0 + g * 4 + rr;
        size_t ob = (size_t)(w * 1024 + row) * 128 + h * 32;
        out[ob + c] = f2b(o0[rr] * inv);
        out[ob + 16 + c] = f2b(o1[rr] * inv);
    }
}

// LayerNorm on fp32 input; writes bf16 (GEMM input) + fp32 (MLP shortcut).
__global__ __launch_bounds__(256) void ln_f(const float* __restrict__ in,
                                            const float* __restrict__ gam,
                                            const float* __restrict__ bet,
                                            unsigned short* __restrict__ outb,
                                            float* __restrict__ outf) {
    int token = blockIdx.x * 4 + (threadIdx.x >> 6);
    int lane = threadIdx.x & 63;
    float2 v = ((const float2*)in)[(size_t)token * 64 + lane];
    float s = v.x + v.y, s2 = v.x * v.x + v.y * v.y;
#pragma unroll
    for (int off = 1; off < 64; off <<= 1) {
        s += __shfl_xor(s, off, 64);
        s2 += __shfl_xor(s2, off, 64);
    }
    float mean = s * (1.f / 128.f);
    float var = s2 * (1.f / 128.f) - mean * mean;
    float inv = rsqrtf(var + 1e-5f);
    float2 gv = ((const float2*)gam)[lane];
    float2 bv = ((const float2*)bet)[lane];
    float y0 = (v.x - mean) * inv * gv.x + bv.x;
    float y1 = (v.y - mean) * inv * gv.y + bv.y;
    ((unsigned int*)outb)[(size_t)token * 64 + lane] =
        (unsigned int)f2b(y0) | ((unsigned int)f2b(y1) << 16);
    ((float2*)outf)[(size_t)token * 64 + lane] = make_float2(y0, y1);
}

// unbind(7)+transpose+partition(32): fp32 ya -> bf16 xb + fp32 xbf
__global__ __launch_bounds__(256) void remap_ab_f(const float* __restrict__ ya,
                                                  unsigned short* __restrict__ xb,
                                                  float* __restrict__ xbf) {
    int t = blockIdx.x * 256 + threadIdx.x;
    int c2 = t & 127;
    int tok = (t >> 7) & 1023;
    int W2 = t >> 17;
    int P = tok >> 5, Q = tok & 31;
    int I = W2 / 7, J = W2 - I * 7;
    int y = I * 32 + P, x2 = J * 32 + Q;
    int f = y * 28672 + x2 * 128 + c2;
    int c = f / 50176;
    int rm = f - c * 50176;
    int i = rm / 1568;
    int r2 = rm - i * 1568;
    int p = r2 / 224;
    int r3 = r2 - p * 224;
    int q = r3 >> 5, j = r3 & 31;
    float val = ya[((size_t)((i * 32 + j) * 49 + p * 7 + q)) * 128 + c];
    xb[t] = f2b(val);
    xbf[t] = val;
}

// unbind(32)+final transpose: fp32 yb -> fp32 out[1,128,224,224]
__global__ __launch_bounds__(256) void remap_out_f(const float* __restrict__ yb,
                                                   float* __restrict__ out) {
    int t = blockIdx.x * 256 + threadIdx.x;
    int c2 = t / 50176;
    int rem = t - c2 * 50176;
    int y = rem / 224;
    int x2 = rem - y * 224;
    int g = y * 28672 + x2 * 128 + c2;
    int c = g / 50176;
    int r = g - c * 50176;
    int I = r / 7168;
    int r2 = r - I * 7168;
    int P = r2 / 224;
    int r3 = r2 - P * 224;
    int Q = r3 / 7, J = r3 - Q * 7;
    out[t] = yb[((size_t)((I * 7 + J) * 1024 + P * 32 + Q)) * 128 + c];
}

// ===========================================================================
// FALLBACK PATH (proven round-7 scalar kernels; used if ws_size too small)
// ===========================================================================
__global__ __launch_bounds__(256) void remap_ab_s(const unsigned short* __restrict__ ya,
                                                  unsigned short* __restrict__ xb) {
    int t = blockIdx.x * 256 + threadIdx.x;
    int c2 = t & 127;
    int tok = (t >> 7) & 1023;
    int W2 = t >> 17;
    int P = tok >> 5, Q = tok & 31;
    int I = W2 / 7, J = W2 - I * 7;
    int y = I * 32 + P, x2 = J * 32 + Q;
    int f = y * 28672 + x2 * 128 + c2;
    int c = f / 50176;
    int rm = f - c * 50176;
    int i = rm / 1568;
    int r2 = rm - i * 1568;
    int p = r2 / 224;
    int r3 = r2 - p * 224;
    int q = r3 >> 5, j = r3 & 31;
    xb[t] = ya[((size_t)((i * 32 + j) * 49 + p * 7 + q)) * 128 + c];
}
__global__ __launch_bounds__(256) void remap_out_s(const unsigned short* __restrict__ yb,
                                                   float* __restrict__ out) {
    int t = blockIdx.x * 256 + threadIdx.x;
    int c2 = t / 50176;
    int rem = t - c2 * 50176;
    int y = rem / 224;
    int x2 = rem - y * 224;
    int g = y * 28672 + x2 * 128 + c2;
    int c = g / 50176;
    int r = g - c * 50176;
    int I = r / 7168;
    int r2 = r - I * 7168;
    int P = r2 / 224;
    int r3 = r2 - P * 224;
    int Q = r3 / 7, J = r3 - Q * 7;
    out[t] = b2f(yb[((size_t)((I * 7 + J) * 1024 + P * 32 + Q)) * 128 + c]);
}
__global__ __launch_bounds__(256) void gemm_w32(const unsigned short* __restrict__ X,
                                                const float* __restrict__ W,
                                                const float* __restrict__ bias,
                                                const unsigned short* __restrict__ res,
                                                unsigned short* __restrict__ Y,
                                                int M, int N, int K) {
    long long t = (long long)blockIdx.x * 256 + threadIdx.x;
    if (t >= (long long)M * N) return;
    int m = (int)(t / N);
    int n = (int)(t - (long long)m * N);
    const unsigned short* xr = X + (size_t)m * K;
    const float* wr = W + (size_t)n * K;
    float acc = bias ? bias[n] : 0.f;
    for (int k = 0; k < K; ++k) acc += b2f(xr[k]) * wr[k];
    if (res) acc += b2f(res[t]);
    Y[t] = f2b(acc);
}
__global__ __launch_bounds__(256) void attn_block7_fused(const unsigned short* __restrict__ xa,
                                                         const float* __restrict__ qw,
                                                         const float* __restrict__ table,
                                                         unsigned short* __restrict__ out) {
    __shared__ unsigned short sx[49 * 128];
    __shared__ float sq[49 * 32], sk[49 * 32], sv[49 * 32];
    __shared__ float ssc[49 * 49];
    const int bx = blockIdx.x;
    const int w = bx >> 2, h = bx & 3;
    const int tid = threadIdx.x;
    for (int u = tid; u < 6272; u += 256) sx[u] = xa[(size_t)(w * 49) * 128 + u];
    __syncthreads();
    for (int e = tid; e < 4704; e += 256) {
        int which = e / 1568;
        int rem = e - which * 1568;
        int n = rem >> 5, d = rem & 31;
        const float* wr = qw + (size_t)(which * 128 + h * 32 + d) * 128;
        const unsigned short* xr = sx + n * 128;
        float acc = 0.f;
        for (int k = 0; k < 128; ++k) acc += b2f(xr[k]) * wr[k];
        if (which == 0) sq[n * 32 + d] = acc;
        else if (which == 1) sk[n * 32 + d] = acc;
        else sv[n * 32 + d] = acc;
    }
    __syncthreads();
    for (int e = tid; e < 2401; e += 256) {
        int i = e / 49, j = e - i * 49;
        float dot = 0.f;
        for (int d = 0; d < 32; ++d) dot += sq[i * 32 + d] * sk[j * 32 + d];
        int ih = i / 7, iw2 = i - ih * 7, jh = j / 7, jw2 = j - jh * 7;
        int idx = (ih - jh + 6) * 13 + (iw2 - jw2 + 6);
        ssc[e] = dot * 5.65685424949238f + table[idx * 4 + h];
    }
    __syncthreads();
    if (tid < 49) {
        float* row = ssc + tid * 49;
        float mx = -1e30f;
        for (int j = 0; j < 49; j++) mx = fmaxf(mx, row[j]);
        float sum = 0.f;
        for (int j = 0; j < 49; j++) { float p = __expf(row[j] - mx); row[j] = p; sum += p; }
        float inv = 1.f / sum;
        for (int j = 0; j < 49; j++) row[j] *= inv;
    }
    __syncthreads();
    for (int e = tid; e < 1568; e += 256) {
        int i = e >> 5, d = e & 31;
        const float* pr = ssc + i * 49;
        float a = 0.f;
        for (int j = 0; j < 49; j++) a += pr[j] * sv[j * 32 + d];
        out[(size_t)(w * 49 + i) * 128 + h * 32 + d] = f2b(a);
    }
}
__global__ __launch_bounds__(256) void kv_head(const unsigned short* __restrict__ xa,
                                               const float* __restrict__ qw,
                                               int h,
                                               unsigned short* __restrict__ kvh) {
    int t = blockIdx.x * 256 + threadIdx.x;
    int tok = t >> 6, e = t & 63;
    int which = (e < 32) ? 1 : 2;
    int d = e & 31;
    const float* wr = qw + (size_t)(which * 128 + h * 32 + d) * 128;
    const unsigned short* xr = xa + (size_t)tok * 128;
    float acc = 0.f;
    for (int k = 0; k < 128; ++k) acc += b2f(xr[k]) * wr[k];
    kvh[t] = f2b(acc);
}
__global__ __launch_bounds__(256) void attn_grid_head(const unsigned short* __restrict__ xa,
                                                      const unsigned short* __restrict__ kvh,
                                                      const float* __restrict__ qw,
                                                      const float* __restrict__ table,
                                                      int h,
                                                      unsigned short* __restrict__ out) {
    __shared__ float sq[32];
    __shared__ float ss[1024];
    __shared__ float red[256];
    __shared__ float pvp[256];
    const int w = blockIdx.x >> 4;
    const int qg = blockIdx.x & 15;
    const int tid = threadIdx.x;
    const float scale = 5.65685424949238f;
    for (int qq = 0; qq < 64; ++qq) {
        const int qi = qg * 64 + qq;
        const int tok = w * 1024 + qi;
        if (tid < 32) {
            const float* wr = qw + (size_t)(h * 32 + tid) * 128;
            const unsigned short* xr = xa + (size_t)tok * 128;
            float acc = 0.f;
            for (int k = 0; k < 128; ++k) acc += b2f(xr[k]) * wr[k];
            sq[tid] = acc;
        }
        __syncthreads();
        const int ihq = qi >> 5, iwq = qi & 31;
        for (int k = tid; k < 1024; k += 256) {
            const unsigned short* kp = kvh + (size_t)(w * 1024 + k) * 64;
            float dot = 0.f;
            for (int d = 0; d < 32; ++d) dot += sq[d] * b2f(kp[d]);
            int jh2 = k >> 5, jw2 = k & 31;
            int idx = (ihq - jh2 + 31) * 63 + (iwq - jw2 + 31);
            ss[k] = dot * scale + table[idx * 4 + h];
        }
        __syncthreads();
        float m = fmaxf(fmaxf(ss[tid], ss[tid + 256]), fmaxf(ss[tid + 512], ss[tid + 768]));
        red[tid] = m;
        __syncthreads();
        for (int s = 128; s > 0; s >>= 1) {
            if (tid < s) red[tid] = fmaxf(red[tid], red[tid + s]);
            __syncthreads();
        }
        m = red[0];
        __syncthreads();
        float ps = 0.f;
        for (int k = tid; k < 1024; k += 256) {
            float p = __expf(ss[k] - m);
            ss[k] = p;
            ps += p;
        }
        red[tid] = ps;
        __syncthreads();
        for (int s = 128; s > 0; s >>= 1) {
            if (tid < s) red[tid] += red[tid + s];
            __syncthreads();
        }
        float l = red[0];
        int kc = tid >> 5, d = tid & 31;
        float a = 0.f;
        const unsigned short* vbase = kvh + (size_t)(w * 1024) * 64 + 32 + d;
        for (int k = kc * 128; k < kc * 128 + 128; ++k) a += ss[k] * b2f(vbase[(size_t)k * 64]);
        pvp[tid] = a;
        __syncthreads();
        if (tid < 32) {
            float o = 0.f;
            for (int c2 = 0; c2 < 8; ++c2) o += pvp[c2 * 32 + tid];
            out[(size_t)tok * 128 + h * 32 + tid] = f2b(o / l);
        }
        __syncthreads();
    }
}
__global__ __launch_bounds__(256) void mlp_fused(const unsigned short* __restrict__ xin,
                                                 const float* __restrict__ fc1w,
                                                 const float* __restrict__ fc1b,
                                                 const float* __restrict__ fc2w,
                                                 const float* __restrict__ fc2b,
                                                 unsigned short* __restrict__ out) {
    __shared__ float sxr[128];
    __shared__ float sh[512];
    const int tok = blockIdx.x;
    const int tid = threadIdx.x;
    if (tid < 128) sxr[tid] = b2f(xin[(size_t)tok * 128 + tid]);
    __syncthreads();
    for (int hh = tid; hh < 512; hh += 256) {
        const float* wr = fc1w + (size_t)hh * 128;
        float acc = fc1b[hh];
        for (int k = 0; k < 128; ++k) acc += sxr[k] * wr[k];
        sh[hh] = acc;
    }
    __syncthreads();
    if (tid < 128) {
        const float* wr = fc2w + (size_t)tid * 512;
        float acc = fc2b[tid];
        for (int k = 0; k < 512; ++k) acc += sh[k] * wr[k];
        out[(size_t)tok * 128 + tid] = f2b(acc + sxr[tid]);
    }
}
__global__ __launch_bounds__(256) void ln_k(const unsigned short* __restrict__ in,
                                            const float* __restrict__ gam,
                                            const float* __restrict__ bet,
                                            unsigned short* __restrict__ out) {
    int token = blockIdx.x * 4 + (threadIdx.x >> 6);
    int lane = threadIdx.x & 63;
    const unsigned int* row = (const unsigned int*)in + (size_t)token * 64;
    unsigned int v = row[lane];
    float x0 = b2f(v), x1 = b2f(v >> 16);
    float s = x0 + x1, s2 = x0 * x0 + x1 * x1;
#pragma unroll
    for (int off = 1; off < 64; off <<= 1) {
        s += __shfl_xor(s, off, 64);
        s2 += __shfl_xor(s2, off, 64);
    }
    float mean = s * (1.f / 128.f);
    float var = s2 * (1.f / 128.f) - mean * mean;
    float inv = rsqrtf(var + 1e-5f);
    float2 gv = ((const float2*)gam)[lane];
    float2 bv = ((const float2*)bet)[lane];
    float y0 = (x0 - mean) * inv * gv.x + bv.x;
    float y1 = (x1 - mean) * inv * gv.y + bv.y;
    ((unsigned int*)out)[(size_t)token * 64 + lane] =
        (unsigned int)f2b(y0) | ((unsigned int)f2b(y1) << 16);
}

// ===========================================================================
extern "C" void kernel_launch(void* const* d_in, const int* in_sizes, int n_in,
                              void* d_out, int out_size, void* d_ws, size_t ws_size,
                              hipStream_t stream) {
    (void)in_sizes; (void)n_in; (void)out_size;
    const float* x = (const float*)d_in[0];
    unsigned short* ws = (unsigned short*)d_ws;
    const int M = 50176;
    dim3 blk(256);
    #define F32(i) ((const float*)d_in[i])

    if (ws_size >= 117178368ull) {
        // ---------------- FAST PATH (MFMA, split weights) ----------------
        unsigned short* WHI = ws;
        unsigned short* WLO = ws + 393216;
        unsigned short* XA  = ws + 786432;
        unsigned short* AT  = ws + 7208960;
        unsigned short* Y2  = ws + 13631488;
        float*          R1  = (float*)(ws + 20054016);
        unsigned short* BIG = ws + 32899072;
        float*          Yf  = (float*)d_out;          // Y1f scratch
        float*          YOB = (float*)XA;             // stage-B fp32 out (XA∪AT)
        float*          TP  = (float*)d_out + 6400000; // grid-bias table (dead window)

        WPtrs wp = {F32(2), F32(3), F32(7), F32(9), F32(12), F32(13), F32(17), F32(19)};
        const size_t oqkv = 0, oproj = 49152, ofc1 = 65536, ofc2 = 131072;
        const size_t goff = 196608;

        conv_w2<<<1536, blk, 0, stream>>>(wp, WHI, WLO);
        gather_in<<<25088, blk, 0, stream>>>(x, XA);

        // ---- stage A ----
        gemm_bt<<<dim3(6, 392), blk, 0, stream>>>(XA, WHI + oqkv, WLO + oqkv, nullptr,
                                                  nullptr, nullptr, BIG, nullptr, M, 384, 128);
        attn_block7<<<4096, blk, 0, stream>>>(BIG, F32(1), AT);
        gemm_bt<<<dim3(2, 392), blk, 0, stream>>>(AT, WHI + oproj, WLO + oproj, F32(4),
                                                  nullptr, x, nullptr, Yf, M, 128, 128);
        ln_f<<<12544, blk, 0, stream>>>(Yf, F32(5), F32(6), Y2, R1);
        gemm_bt<<<dim3(8, 392), blk, 0, stream>>>(Y2, WHI + ofc1, WLO + ofc1, F32(8),
                                                  nullptr, nullptr, BIG, nullptr, M, 512, 128);
        gemm_bt<<<dim3(2, 392), blk, 0, stream>>>(BIG, WHI + ofc2, WLO + ofc2, F32(10),
                                                  R1, nullptr, nullptr, Yf, M, 128, 512);
        remap_ab_f<<<25088, blk, 0, stream>>>(Yf, XA, R1);

        // ---- stage B ----
        conv_bias<<<63, blk, 0, stream>>>(F32(11), TP);  // d_out tail is dead here
        gemm_bt<<<dim3(6, 392), blk, 0, stream>>>(XA, WHI + goff + oqkv, WLO + goff + oqkv,
                                                  nullptr, nullptr, nullptr, BIG, nullptr, M, 384, 128);
        attn_grid32<<<3136, blk, 0, stream>>>(BIG, TP, AT);
        gemm_bt<<<dim3(2, 392), blk, 0, stream>>>(AT, WHI + goff + oproj, WLO + goff + oproj,
                                                  F32(14), R1, nullptr, nullptr, Yf, M, 128, 128);
        ln_f<<<12544, blk, 0, stream>>>(Yf, F32(15), F32(16), Y2, R1);
        gemm_bt<<<dim3(8, 392), blk, 0, stream>>>(Y2, WHI + goff + ofc1, WLO + goff + ofc1,
                                                  F32(18), nullptr, nullptr, BIG, nullptr, M, 512, 128);
        gemm_bt<<<dim3(2, 392), blk, 0, stream>>>(BIG, WHI + goff + ofc2, WLO + goff + ofc2,
                                                  F32(20), R1, nullptr, nullptr, YOB, M, 128, 512);
        remap_out_f<<<25088, blk, 0, stream>>>(YOB, (float*)d_out);
    } else {
        // ---------------- FALLBACK (proven round-7 scalar path) ----------------
        unsigned short* XA  = ws;
        unsigned short* AT  = XA + 6422528;
        unsigned short* KVh = AT + 6422528;
        unsigned short* Yd  = (unsigned short*)d_out;

        gather_in<<<25088, blk, 0, stream>>>(x, XA);
        attn_block7_fused<<<4096, blk, 0, stream>>>(XA, F32(2), F32(1), AT);
        gemm_w32<<<25088, blk, 0, stream>>>(AT, F32(3), F32(4), XA, Yd, M, 128, 128);
        ln_k<<<12544, blk, 0, stream>>>(Yd, F32(5), F32(6), Yd);
        mlp_fused<<<50176, blk, 0, stream>>>(Yd, F32(7), F32(8), F32(9), F32(10), AT);
        remap_ab_s<<<25088, blk, 0, stream>>>(AT, XA);
        for (int h = 0; h < 4; ++h) {
            kv_head<<<12544, blk, 0, stream>>>(XA, F32(12), h, KVh);
            attn_grid_head<<<784, blk, 0, stream>>>(XA, KVh, F32(12), F32(11), h, AT);
        }
        gemm_w32<<<25088, blk, 0, stream>>>(AT, F32(13), F32(14), XA, Yd, M, 128, 128);
        ln_k<<<12544, blk, 0, stream>>>(Yd, F32(15), F32(16), Yd);
        mlp_fused<<<50176, blk, 0, stream>>>(Yd, F32(17), F32(18), F32(19), F32(20), AT);
        remap_out_s<<<25088, blk, 0, stream>>>(AT, (float*)d_out);
    }
    #undef F32
}